// Round 6
// baseline (603.716 us; speedup 1.0000x reference)
//
#include <hip/hip_runtime.h>
#include <hip/hip_bf16.h>
#include <math.h>

// ---------------------------------------------------------------------------
// EvolveGCNH + GCNConv + EdgeDecoder.
// R1: atomic scatter -> dst-CSR register gather (3574 -> 1223 us).
// R5: parallel top-k, merged CSR builds, dual GEMM (962 us).
// R7: two-phase bucket sort for both CSRs (609 us).
// R8: QUAD decomposition gather/decode + kernel fusion (522 us).
// R11: merged p2 + fused score_cast (510 us).
// R12: DPP reduce in decode, m97-structure GEMMs, 3-stage prefetch (476 us).
// R13/R14: per-chunk meta PRELOAD + shfl broadcast + esv_scale (467 us).
// R15: persistent waves REGRESSED (471): decode/gather are at the ~6.3TB/s
//      gather-path throughput wall (440MB/65us each); latency knobs exhausted.
// R16: launch collapse 16->11 — container failed twice (same infra error
//      string as R13, which passed unchanged on resubmit).
// R17 (this round): R16 de-risked — the one novel sync construct
//      (last-block-done fused hist+scan) reverted to the proven two-kernel
//      pair; all other fusions kept (init=zero+lin1cast, hist folded into
//      score_cast, p1 pair fused, dinv applied at gather meta-preload).
//      12 launches vs R14's 16.
// ---------------------------------------------------------------------------

typedef __attribute__((ext_vector_type(8))) short bf16x8;
typedef __attribute__((ext_vector_type(8))) unsigned short u16x8;
typedef __attribute__((ext_vector_type(4))) float f32x4;

#define WSHIFT 9              // 512 nodes per bucket
#define WMASK 511
#define NBUCK 98              // ceil(50000/512)

__device__ __forceinline__ unsigned f2key(float f) {
  unsigned u = __float_as_uint(f);
  return (u & 0x80000000u) ? ~u : (u | 0x80000000u);
}

// round-to-nearest-even fp32 -> bf16 bits
__device__ __forceinline__ unsigned short f2bf(float f) {
  unsigned u = __float_as_uint(f);
  unsigned r = u + 0x7fffu + ((u >> 16) & 1u);
  return (unsigned short)(r >> 16);
}
__device__ __forceinline__ float bf2f(unsigned short h) {
  return __uint_as_float((unsigned)h << 16);
}

// DPP row-rotate add: sums within each 16-lane row after ror 8,4,2,1.
template <int CTRL>
__device__ __forceinline__ float dpp_add(float s) {
  int t = __builtin_amdgcn_update_dpp(0, __float_as_int(s), CTRL, 0xf, 0xf, false);
  return s + __int_as_float(t);
}

// async global->LDS, 16B per lane; lds ptr must be wave-uniform.
__device__ __forceinline__ void gload16(const void* g, void* l) {
  __builtin_amdgcn_global_load_lds((const __attribute__((address_space(1))) void*)g,
                                   (__attribute__((address_space(3))) void*)l, 16, 0, 0);
}

// blocks 0..511: lin1_w [256][512] -> stacked BT (WA^T rows 0..255, WB^T
// rows 256..511). blocks 512+: zero the ghist|bcnt region.
__global__ __launch_bounds__(256) void init_kernel(const float* __restrict__ lin1,
                                                   unsigned short* __restrict__ WAB,
                                                   int4* __restrict__ zb, int nz4) {
  int b = blockIdx.x, tid = threadIdx.x;
  if (b < 512) {
    int idx = b * 256 + tid;
    int n = idx >> 9, k = idx & 511;
    unsigned short h = f2bf(lin1[idx]);
    if (k < 256)
      WAB[n * 256 + k] = h;
    else
      WAB[(256 + n) * 256 + (k - 256)] = h;
  } else {
    int j = (b - 512) * 256 + tid;
    if (j < nz4) zb[j] = make_int4(0, 0, 0, 0);
  }
}

// score (incl. ||p||) + bf16 cast of x + global 4096-bin key histogram,
// all in one pass over x (one atomic per wave).
__global__ __launch_bounds__(256) void score_cast_kernel(const float* __restrict__ x,
                                                         const float* __restrict__ p,
                                                         float* __restrict__ score,
                                                         unsigned short* __restrict__ xh,
                                                         int* __restrict__ gh, int N) {
  int node = blockIdx.x * 4 + (threadIdx.x >> 6);
  int lane = threadIdx.x & 63;
  if (node >= N) return;
  float4 xv = ((const float4*)(x + (size_t)node * 256))[lane];
  ushort4 hv;
  hv.x = f2bf(xv.x);
  hv.y = f2bf(xv.y);
  hv.z = f2bf(xv.z);
  hv.w = f2bf(xv.w);
  ((ushort4*)(xh + (size_t)node * 256))[lane] = hv;
  float4 pv = ((const float4*)p)[lane];
  float s = xv.x * pv.x + xv.y * pv.y + xv.z * pv.z + xv.w * pv.w;
  float sp = pv.x * pv.x + pv.y * pv.y + pv.z * pv.z + pv.w * pv.w;
#pragma unroll
  for (int off = 32; off > 0; off >>= 1) {
    s += __shfl_down(s, off, 64);
    sp += __shfl_down(sp, off, 64);
  }
  if (lane == 0) {
    float sc = s / sqrtf(sp);
    score[node] = sc;
    atomicAdd(&gh[f2key(sc) >> 20], 1);
  }
}

// select (suffix-scan over 4096-bin histogram -> bin-floor threshold) fused
// with collect + bitonic sort (key desc, idx asc) -> perm[k], tanh(score).
__global__ __launch_bounds__(1024) void topk_kernel(const float* __restrict__ score, int n, int k,
                                                    const int* __restrict__ gh,
                                                    int* __restrict__ perm,
                                                    float* __restrict__ tts) {
  __shared__ int part[1024];
  __shared__ unsigned sT;
  int tid = threadIdx.x;
  {
    int b0 = tid * 4;
    int s0 = gh[b0], s1 = gh[b0 + 1], s2 = gh[b0 + 2], s3 = gh[b0 + 3];
    part[tid] = s0 + s1 + s2 + s3;
    __syncthreads();
    for (int off = 1; off < 1024; off <<= 1) {
      int v = part[tid];
      int add = (tid + off < 1024) ? part[tid + off] : 0;
      __syncthreads();
      part[tid] = v + add;
      __syncthreads();
    }
    int sufChunk = part[tid];
    int sufNext = (tid < 1023) ? part[tid + 1] : 0;
    if (sufNext < k && sufChunk >= k) {
      int run = sufNext;
      int b;
      run += s3;
      if (run >= k) b = b0 + 3;
      else {
        run += s2;
        if (run >= k) b = b0 + 2;
        else {
          run += s1;
          b = (run >= k) ? b0 + 1 : b0;
        }
      }
      sT = ((unsigned)b) << 20;
    }
  }
  __syncthreads();
  unsigned T = sT;
  __shared__ unsigned keys[1024];
  __shared__ int idxs[1024];
  __shared__ int cnt;
  if (tid == 0) cnt = 0;
  keys[tid] = 0u;
  idxs[tid] = 0x7fffffff;
  __syncthreads();
  for (int i = tid; i < n; i += 1024) {
    unsigned key = f2key(score[i]);
    if (key >= T) {
      int p = atomicAdd(&cnt, 1);
      if (p < 1024) { keys[p] = key; idxs[p] = i; }
    }
  }
  __syncthreads();
  for (int size = 2; size <= 1024; size <<= 1) {
    for (int stride = size >> 1; stride > 0; stride >>= 1) {
      int j = tid ^ stride;
      if (j > tid) {
        unsigned ka = keys[tid], kb = keys[j];
        int ia = idxs[tid], ib = idxs[j];
        bool aBefore = (ka > kb) || (ka == kb && ia < ib);
        bool up = ((tid & size) == 0);
        if (aBefore != up) {
          keys[tid] = kb; keys[j] = ka;
          idxs[tid] = ib; idxs[j] = ia;
        }
      }
      __syncthreads();
    }
  }
  if (tid < k) {
    int idx = idxs[tid];
    perm[tid] = idx;
    tts[tid] = tanhf(score[idx]);
  }
}

// GRU step with x_tilde computed inline (row i = x[perm[i]] * tts[i]);
// writes evolved W TRANSPOSED as bf16: WevoT[n*256 + k] = bf16(W[k][n])
__global__ __launch_bounds__(256) void gru_kernel(const float* __restrict__ x,
                                                  const int* __restrict__ perm,
                                                  const float* __restrict__ tts,
                                                  const float* __restrict__ Wi,
                                                  const float* __restrict__ W_ih,
                                                  const float* __restrict__ W_hh,
                                                  const float* __restrict__ b_ih,
                                                  const float* __restrict__ b_hh,
                                                  unsigned short* __restrict__ WevoT) {
  int i = blockIdx.x, j = threadIdx.x;  // i = k-row of W, j = n-col
  __shared__ float sx[256], sh[256];
  sx[j] = x[(size_t)perm[i] * 256 + j] * tts[i];
  sh[j] = Wi[i * 256 + j];
  __syncthreads();
  float gi[3], gh[3];
#pragma unroll
  for (int g = 0; g < 3; ++g) {
    int row = g * 256 + j;
    const float4* wi4 = (const float4*)(W_ih + (size_t)row * 256);
    const float4* wh4 = (const float4*)(W_hh + (size_t)row * 256);
    float si = 0.f, s2 = 0.f;
    for (int k4 = 0; k4 < 64; ++k4) {
      float4 wv = wi4[k4];
      float4 hv = wh4[k4];
      int k = k4 * 4;
      si += sx[k] * wv.x + sx[k + 1] * wv.y + sx[k + 2] * wv.z + sx[k + 3] * wv.w;
      s2 += sh[k] * hv.x + sh[k + 1] * hv.y + sh[k + 2] * hv.z + sh[k + 3] * hv.w;
    }
    gi[g] = si + b_ih[row];
    gh[g] = s2 + b_hh[row];
  }
  float r = 1.f / (1.f + expf(-(gi[0] + gh[0])));
  float z = 1.f / (1.f + expf(-(gi[1] + gh[1])));
  float nn = tanhf(gi[2] + r * gh[2]);
  float w = (1.f - z) * nn + z * sh[j];
  WevoT[(size_t)j * 256 + i] = f2bf(w);
}

// ---------------------------------------------------------------------------
// m97-structure bf16 MFMA GEMM: per blockIdx.y,
//   C[M,256] = A[M,256] @ (BT[by*256 .. by*256+255][256])^T   (bf16 in/out)
// 128x256 tile, 8 waves (2 wm x 4 wn), BK=32, global_load_lds staging,
// 2-barrier K-loop. Rows >= M read in-workspace garbage (never written back).
// ---------------------------------------------------------------------------
__global__ __launch_bounds__(512) void mfma_gemm128(const unsigned short* __restrict__ A,
                                                    const unsigned short* __restrict__ BT,
                                                    unsigned short* __restrict__ C1,
                                                    unsigned short* __restrict__ C2,
                                                    int M) {
  __shared__ unsigned short sA[128 * 32];
  __shared__ unsigned short sB[256 * 32];
  int tid = threadIdx.x;
  int wave = tid >> 6, lane = tid & 63;
  int quad = lane >> 4, r16 = lane & 15;
  int wm = wave >> 2, wn = wave & 3;
  int mbase = blockIdx.x * 128;
  const unsigned short* Bt = BT + ((size_t)blockIdx.y << 16);
  unsigned short* Cout = blockIdx.y ? C2 : C1;

  // staging map: thread t stages 16B -> LDS byte t*16 (= row t>>2, colq t&3)
  int srow = tid >> 2, scolq = tid & 3;
  const unsigned short* gA = A + (size_t)(mbase + srow) * 256 + scolq * 8;
  const unsigned short* gB0 = Bt + (size_t)srow * 256 + scolq * 8;
  const unsigned short* gB1 = Bt + (size_t)(128 + srow) * 256 + scolq * 8;
  unsigned short* lA = sA + wave * 512;          // wave-uniform LDS bases
  unsigned short* lB0 = sB + wave * 512;
  unsigned short* lB1 = sB + 4096 + wave * 512;

  f32x4 acc[4][4];
#pragma unroll
  for (int i = 0; i < 4; ++i)
#pragma unroll
    for (int j = 0; j < 4; ++j) acc[i][j] = (f32x4){0.f, 0.f, 0.f, 0.f};

  const unsigned short* pA = sA + (wm * 64 + r16) * 32 + quad * 8;
  const unsigned short* pB = sB + (wn * 64 + r16) * 32 + quad * 8;

  for (int k0 = 0; k0 < 256; k0 += 32) {
    if (k0) __syncthreads();              // prior compute done before overwrite
    gload16(gA + k0, lA);
    gload16(gB0 + k0, lB0);
    gload16(gB1 + k0, lB1);
    __syncthreads();                      // drains vmcnt -> staging complete
    bf16x8 af[4], bfr[4];
#pragma unroll
    for (int mt = 0; mt < 4; ++mt) af[mt] = *(const bf16x8*)(pA + mt * 512);
#pragma unroll
    for (int nt = 0; nt < 4; ++nt) bfr[nt] = *(const bf16x8*)(pB + nt * 512);
#pragma unroll
    for (int mt = 0; mt < 4; ++mt)
#pragma unroll
      for (int nt = 0; nt < 4; ++nt)
        acc[mt][nt] = __builtin_amdgcn_mfma_f32_16x16x32_bf16(af[mt], bfr[nt], acc[mt][nt], 0, 0, 0);
  }
#pragma unroll
  for (int mt = 0; mt < 4; ++mt) {
#pragma unroll
    for (int rr = 0; rr < 4; ++rr) {
      int grow = mbase + wm * 64 + mt * 16 + quad * 4 + rr;
      if (grow < M) {
#pragma unroll
        for (int nt = 0; nt < 4; ++nt)
          Cout[(size_t)grow * 256 + wn * 64 + nt * 16 + r16] = f2bf(acc[mt][nt][rr]);
      }
    }
  }
}

// ---- two-phase bucket sort for both CSRs (98 buckets, 512 nodes each) ------

// phase 0: bucket histogram for conv-dst and decoder-src (LDS-aggregated)
__global__ __launch_bounds__(256) void bucket_hist_kernel(const int* __restrict__ ei,
                                                          const int* __restrict__ ewi,
                                                          int* __restrict__ bcnt1,
                                                          int* __restrict__ bcnt2, int E) {
  __shared__ int c1[128], c2[128];
  int tid = threadIdx.x;
  if (tid < 128) { c1[tid] = 0; c2[tid] = 0; }
  __syncthreads();
  int idx = blockIdx.x * 256 + tid;
  int stride = gridDim.x * 256;
  for (int e = idx; e < E; e += stride) {
    atomicAdd(&c1[ei[E + e] >> WSHIFT], 1);
    atomicAdd(&c2[ewi[e] >> WSHIFT], 1);
  }
  __syncthreads();
  if (tid < 128) {
    if (c1[tid]) atomicAdd(&bcnt1[tid], c1[tid]);
    if (c2[tid]) atomicAdd(&bcnt2[tid], c2[tid]);
  }
}

// phase 0b: scan bucket counts -> bases + cursors; also rowp[N] = E
__global__ __launch_bounds__(128) void bucket_scan_kernel(const int* __restrict__ bcnt1,
                                                          const int* __restrict__ bcnt2,
                                                          int* __restrict__ bbase1,
                                                          int* __restrict__ bbase2,
                                                          int* __restrict__ gcur1,
                                                          int* __restrict__ gcur2,
                                                          int* __restrict__ rowp1,
                                                          int* __restrict__ rowp2, int N, int E) {
  __shared__ int ss[128];
  int tid = threadIdx.x;
  // CSR 1
  int v = (tid < NBUCK) ? bcnt1[tid] : 0;
  ss[tid] = v;
  __syncthreads();
  for (int off = 1; off < 128; off <<= 1) {
    int a = ss[tid];
    int b = (tid >= off) ? ss[tid - off] : 0;
    __syncthreads();
    ss[tid] = a + b;
    __syncthreads();
  }
  int excl = ss[tid] - v;
  if (tid < NBUCK) { bbase1[tid] = excl; gcur1[tid] = excl; }
  if (tid == NBUCK - 1) bbase1[NBUCK] = excl + v;
  __syncthreads();
  // CSR 2
  v = (tid < NBUCK) ? bcnt2[tid] : 0;
  ss[tid] = v;
  __syncthreads();
  for (int off = 1; off < 128; off <<= 1) {
    int a = ss[tid];
    int b = (tid >= off) ? ss[tid - off] : 0;
    __syncthreads();
    ss[tid] = a + b;
    __syncthreads();
  }
  excl = ss[tid] - v;
  if (tid < NBUCK) { bbase2[tid] = excl; gcur2[tid] = excl; }
  if (tid == NBUCK - 1) bbase2[NBUCK] = excl + v;
  if (tid == 0) { rowp1[N] = E; rowp2[N] = E; }
}

// phase 1 fused (conv blocks [0,nb), decoder blocks [nb,2nb)): tile-ranked
// scatter into bucket staging, 4096 edges/block.
// conv:  stage.x = src | (dstLocal<<16), stage.y = attr bits
// dec:   stage.x = dst | (srcLocal<<16), stage.y = edge_id
__global__ __launch_bounds__(256) void p1_both_kernel(const int* __restrict__ ei,
                                                      const float* __restrict__ attr,
                                                      int* __restrict__ gcur1,
                                                      int2* __restrict__ stage1,
                                                      const int* __restrict__ ewi,
                                                      int* __restrict__ gcur2,
                                                      int2* __restrict__ stage2,
                                                      int E, int nb) {
  __shared__ int cnt[128], cur[128];
  int tid = threadIdx.x;
  bool conv = blockIdx.x < nb;
  int base = (conv ? blockIdx.x : blockIdx.x - nb) * 4096;
  int* gcur = conv ? gcur1 : gcur2;
  int2* stage = conv ? stage1 : stage2;
  if (tid < 128) cnt[tid] = 0;
  __syncthreads();
  int bk[16];
  int2 pl[16];
#pragma unroll
  for (int i = 0; i < 16; ++i) {
    int e = base + i * 256 + tid;
    bk[i] = -1;
    if (e < E) {
      if (conv) {
        int d = ei[E + e];
        int s = ei[e];
        bk[i] = d >> WSHIFT;
        pl[i] = make_int2(s | ((d & WMASK) << 16), __float_as_int(attr[e]));
      } else {
        int s = ewi[e];
        int d = ewi[E + e];
        bk[i] = s >> WSHIFT;
        pl[i] = make_int2(d | ((s & WMASK) << 16), e);
      }
      atomicAdd(&cnt[bk[i]], 1);
    }
  }
  __syncthreads();
  if (tid < NBUCK) {
    int c = cnt[tid];
    cur[tid] = c ? atomicAdd(&gcur[tid], c) : 0;
  }
  __syncthreads();
#pragma unroll
  for (int i = 0; i < 16; ++i) {
    if (bk[i] >= 0) {
      int pos = atomicAdd(&cur[bk[i]], 1);
      stage[pos] = pl[i];
    }
  }
}

// phase 2 (both CSRs, gridDim.x = 2*NBUCK = 196): one block per bucket.
// LDS 512-bin node histogram (+deg for conv), scan, node-ordered CSR write.
__global__ __launch_bounds__(256) void p2_kernel(const int2* __restrict__ stage1,
                                                 const int* __restrict__ bbase1,
                                                 int2* __restrict__ esv,
                                                 int* __restrict__ rowp1,
                                                 float* __restrict__ dinv,
                                                 const int2* __restrict__ stage2,
                                                 const int* __restrict__ bbase2,
                                                 int2* __restrict__ eto,
                                                 int* __restrict__ rowp2, int N) {
  __shared__ int cnt[512];
  __shared__ float degs[512];
  __shared__ int pref[512];
  __shared__ int ss[256];
  int tid = threadIdx.x;
  bool isConv = blockIdx.x < NBUCK;
  int b = isConv ? blockIdx.x : blockIdx.x - NBUCK;
  const int2* stage = isConv ? stage1 : stage2;
  const int* bbase = isConv ? bbase1 : bbase2;
  int beg = bbase[b], end = bbase[b + 1];
  int node0 = b << WSHIFT;
  cnt[tid] = 0; cnt[tid + 256] = 0;
  degs[tid] = 0.f; degs[tid + 256] = 0.f;
  __syncthreads();
  for (int j = beg + tid; j < end; j += 256) {
    int2 p = stage[j];
    int loc = p.x >> 16;
    atomicAdd(&cnt[loc], 1);
    if (isConv) atomicAdd(&degs[loc], __int_as_float(p.y));
  }
  __syncthreads();
  // exclusive scan over 512 bins (each thread owns 2 consecutive)
  int c0 = cnt[2 * tid], c1 = cnt[2 * tid + 1];
  ss[tid] = c0 + c1;
  __syncthreads();
  for (int off = 1; off < 256; off <<= 1) {
    int a = ss[tid];
    int bb = (tid >= off) ? ss[tid - off] : 0;
    __syncthreads();
    ss[tid] = a + bb;
    __syncthreads();
  }
  int excl = (tid ? ss[tid - 1] : 0);
  pref[2 * tid] = excl;
  pref[2 * tid + 1] = excl + c0;
  __syncthreads();
#pragma unroll
  for (int h = 0; h < 2; ++h) {
    int i = tid + h * 256;
    int node = node0 + i;
    if (node < N) {
      if (isConv) {
        rowp1[node] = beg + pref[i];
        float d = degs[i];
        dinv[node] = d > 0.f ? 1.f / sqrtf(d) : 0.f;
      } else {
        rowp2[node] = beg + pref[i];
      }
    }
  }
  __syncthreads();
  int2* outb = isConv ? esv : eto;
  for (int j = beg + tid; j < end; j += 256) {
    int2 p = stage[j];
    int loc = p.x >> 16;
    int pos = beg + atomicAdd(&pref[loc], 1);
    outb[pos] = make_int2(p.x & 0xFFFF, p.y);
  }
}

// one wave per dst node, quad decomposition: 16 lanes/edge x 4 edges/group.
// Per 64-edge chunk: lane l coalesced-loads meta esv[cb+l] and applies
// dinv[src] once (L2-resident), then stage refills broadcast src/v via shfl
// (refill chain rows-only). 3-stage in-place prefetch.
__global__ __launch_bounds__(256) void gcn_gather(const unsigned short* __restrict__ xw,
                                                  const int* __restrict__ row_ptr,
                                                  const int2* __restrict__ esv,
                                                  const float* __restrict__ dinv,
                                                  unsigned short* __restrict__ ne, int N) {
  int node = blockIdx.x * 4 + (threadIdx.x >> 6);
  int lane = threadIdx.x & 63;
  int g = lane & 15, q = lane >> 4;
  if (node >= N) return;
  int beg = row_ptr[node], end = row_ptr[node + 1];
  float acc[16];
#pragma unroll
  for (int c = 0; c < 16; ++c) acc[c] = 0.f;
  const unsigned short* xb = xw + g * 16;

  for (int cb = beg; cb < end; cb += 64) {
    int cend = cb + 64 < end ? cb + 64 : end;
    int me = cb + lane;
    int2 mm = (me < cend) ? esv[me] : make_int2(0, 0);
    int mx = mm.x;
    float mv = __int_as_float(mm.y) * dinv[mx];

    float vA = 0.f, vB = 0.f, vC = 0.f;
    u16x8 rAa, rAb, rBa, rBb, rCa, rCb;
    {
      int e = cb + q;
      int sx = __shfl(mx, q, 64);
      float tv = __shfl(mv, q, 64);
      vA = (e < cend) ? tv : 0.f;
      rAa = *(const u16x8*)(xb + (size_t)sx * 256);
      rAb = *(const u16x8*)(xb + (size_t)sx * 256 + 8);
    }
    if (cb + 4 < cend) {
      int e = cb + 4 + q;
      int sx = __shfl(mx, 4 + q, 64);
      float tv = __shfl(mv, 4 + q, 64);
      vB = (e < cend) ? tv : 0.f;
      rBa = *(const u16x8*)(xb + (size_t)sx * 256);
      rBb = *(const u16x8*)(xb + (size_t)sx * 256 + 8);
    } else { rBa = rAa; rBb = rAb; }
    if (cb + 8 < cend) {
      int e = cb + 8 + q;
      int sx = __shfl(mx, 8 + q, 64);
      float tv = __shfl(mv, 8 + q, 64);
      vC = (e < cend) ? tv : 0.f;
      rCa = *(const u16x8*)(xb + (size_t)sx * 256);
      rCb = *(const u16x8*)(xb + (size_t)sx * 256 + 8);
    } else { rCa = rAa; rCb = rAb; }

    for (int jb = cb; jb < cend; jb += 12) {
      // consume A, refill A <- jb+12
#pragma unroll
      for (int c = 0; c < 8; ++c) acc[c] += bf2f(rAa[c]) * vA;
#pragma unroll
      for (int c = 0; c < 8; ++c) acc[8 + c] += bf2f(rAb[c]) * vA;
      vA = 0.f;
      if (jb + 12 < cend) {
        int e = jb + 12 + q;
        int idx = (e - cb) & 63;
        int sx = __shfl(mx, idx, 64);
        float tv = __shfl(mv, idx, 64);
        vA = (e < cend) ? tv : 0.f;
        rAa = *(const u16x8*)(xb + (size_t)sx * 256);
        rAb = *(const u16x8*)(xb + (size_t)sx * 256 + 8);
      }
      // consume B, refill B <- jb+16
#pragma unroll
      for (int c = 0; c < 8; ++c) acc[c] += bf2f(rBa[c]) * vB;
#pragma unroll
      for (int c = 0; c < 8; ++c) acc[8 + c] += bf2f(rBb[c]) * vB;
      vB = 0.f;
      if (jb + 16 < cend) {
        int e = jb + 16 + q;
        int idx = (e - cb) & 63;
        int sx = __shfl(mx, idx, 64);
        float tv = __shfl(mv, idx, 64);
        vB = (e < cend) ? tv : 0.f;
        rBa = *(const u16x8*)(xb + (size_t)sx * 256);
        rBb = *(const u16x8*)(xb + (size_t)sx * 256 + 8);
      }
      // consume C, refill C <- jb+20
#pragma unroll
      for (int c = 0; c < 8; ++c) acc[c] += bf2f(rCa[c]) * vC;
#pragma unroll
      for (int c = 0; c < 8; ++c) acc[8 + c] += bf2f(rCb[c]) * vC;
      vC = 0.f;
      if (jb + 20 < cend) {
        int e = jb + 20 + q;
        int idx = (e - cb) & 63;
        int sx = __shfl(mx, idx, 64);
        float tv = __shfl(mv, idx, 64);
        vC = (e < cend) ? tv : 0.f;
        rCa = *(const u16x8*)(xb + (size_t)sx * 256);
        rCb = *(const u16x8*)(xb + (size_t)sx * 256 + 8);
      }
    }
  }
  // cross-quad combine (each quad holds a partial over the same channels)
#pragma unroll
  for (int c = 0; c < 16; ++c) {
    acc[c] += __shfl_xor(acc[c], 16, 64);
    acc[c] += __shfl_xor(acc[c], 32, 64);
  }
  if (q == 0) {
    float dd = dinv[node];
    u16x8 o0, o1;
#pragma unroll
    for (int c = 0; c < 8; ++c) {
      o0[c] = f2bf(acc[c] * dd);
      o1[c] = f2bf(acc[8 + c] * dd);
    }
    *(u16x8*)(ne + (size_t)node * 256 + g * 16) = o0;
    *(u16x8*)(ne + (size_t)node * 256 + g * 16 + 8) = o1;
  }
}

// decode grouped by src, one wave per node, quad decomposition. Per-chunk
// meta preload + shfl broadcast; 3-stage in-place prefetch; DPP row_ror
// reduce. A[s]+b1 and w2 register-resident per lane (16 channels).
__global__ __launch_bounds__(256) void edge_decode_csr(const unsigned short* __restrict__ A,
                                                       const unsigned short* __restrict__ Bm,
                                                       const int* __restrict__ row_ptr,
                                                       const int2* __restrict__ eto,
                                                       const float* __restrict__ b1,
                                                       const float* __restrict__ w2,
                                                       const float* __restrict__ b2,
                                                       float* __restrict__ out, int N) {
  int node = blockIdx.x * 4 + (threadIdx.x >> 6);
  int lane = threadIdx.x & 63;
  int g = lane & 15, q = lane >> 4;
  if (node >= N) return;
  int beg = row_ptr[node], end = row_ptr[node + 1];
  if (beg >= end) return;
  float a[16], w[16];
  {
    u16x8 a0 = *(const u16x8*)(A + (size_t)node * 256 + g * 16);
    u16x8 a1 = *(const u16x8*)(A + (size_t)node * 256 + g * 16 + 8);
    const float4* bp = (const float4*)(b1 + g * 16);
    const float4* wp = (const float4*)(w2 + g * 16);
#pragma unroll
    for (int i = 0; i < 4; ++i) {
      float4 bv = bp[i];
      float4 wv = wp[i];
      a[i * 4 + 0] = (i < 2 ? bf2f(a0[i * 4 + 0]) : bf2f(a1[i * 4 - 8])) + bv.x;
      a[i * 4 + 1] = (i < 2 ? bf2f(a0[i * 4 + 1]) : bf2f(a1[i * 4 - 7])) + bv.y;
      a[i * 4 + 2] = (i < 2 ? bf2f(a0[i * 4 + 2]) : bf2f(a1[i * 4 - 6])) + bv.z;
      a[i * 4 + 3] = (i < 2 ? bf2f(a0[i * 4 + 3]) : bf2f(a1[i * 4 - 5])) + bv.w;
      w[i * 4 + 0] = wv.x;
      w[i * 4 + 1] = wv.y;
      w[i * 4 + 2] = wv.z;
      w[i * 4 + 3] = wv.w;
    }
  }
  float base = b2[0];
  const unsigned short* Bb = Bm + g * 16;

  for (int cb = beg; cb < end; cb += 64) {
    int cend = cb + 64 < end ? cb + 64 : end;
    int me = cb + lane;
    int2 mm = (me < cend) ? eto[me] : make_int2(0, 0);
    int mx = mm.x, my = mm.y;

    bool okA = false, okB = false, okC = false;
    int oA = 0, oB = 0, oC = 0;
    u16x8 rAa, rAb, rBa, rBb, rCa, rCb;
    {
      int e = cb + q;
      int sx = __shfl(mx, q, 64);
      oA = __shfl(my, q, 64);
      okA = e < cend;
      rAa = *(const u16x8*)(Bb + (size_t)sx * 256);
      rAb = *(const u16x8*)(Bb + (size_t)sx * 256 + 8);
    }
    if (cb + 4 < cend) {
      int e = cb + 4 + q;
      int sx = __shfl(mx, 4 + q, 64);
      oB = __shfl(my, 4 + q, 64);
      okB = e < cend;
      rBa = *(const u16x8*)(Bb + (size_t)sx * 256);
      rBb = *(const u16x8*)(Bb + (size_t)sx * 256 + 8);
    } else { rBa = rAa; rBb = rAb; }
    if (cb + 8 < cend) {
      int e = cb + 8 + q;
      int sx = __shfl(mx, 8 + q, 64);
      oC = __shfl(my, 8 + q, 64);
      okC = e < cend;
      rCa = *(const u16x8*)(Bb + (size_t)sx * 256);
      rCb = *(const u16x8*)(Bb + (size_t)sx * 256 + 8);
    } else { rCa = rAa; rCb = rAb; }

    for (int jb = cb; jb < cend; jb += 12) {
      // consume A
      {
        float s0 = 0.f, s1 = 0.f;
#pragma unroll
        for (int c = 0; c < 8; ++c) s0 += fmaxf(a[c] + bf2f(rAa[c]), 0.f) * w[c];
#pragma unroll
        for (int c = 0; c < 8; ++c) s1 += fmaxf(a[8 + c] + bf2f(rAb[c]), 0.f) * w[8 + c];
        float s = s0 + s1;
        s = dpp_add<0x128>(s);  // row_ror:8
        s = dpp_add<0x124>(s);  // row_ror:4
        s = dpp_add<0x122>(s);  // row_ror:2
        s = dpp_add<0x121>(s);  // row_ror:1
        if (g == 0 && okA) out[oA] = s + base;
      }
      // refill A <- jb+12
      okA = false;
      if (jb + 12 < cend) {
        int e = jb + 12 + q;
        int idx = (e - cb) & 63;
        int sx = __shfl(mx, idx, 64);
        oA = __shfl(my, idx, 64);
        okA = e < cend;
        rAa = *(const u16x8*)(Bb + (size_t)sx * 256);
        rAb = *(const u16x8*)(Bb + (size_t)sx * 256 + 8);
      }
      // consume B
      {
        float s0 = 0.f, s1 = 0.f;
#pragma unroll
        for (int c = 0; c < 8; ++c) s0 += fmaxf(a[c] + bf2f(rBa[c]), 0.f) * w[c];
#pragma unroll
        for (int c = 0; c < 8; ++c) s1 += fmaxf(a[8 + c] + bf2f(rBb[c]), 0.f) * w[8 + c];
        float s = s0 + s1;
        s = dpp_add<0x128>(s);
        s = dpp_add<0x124>(s);
        s = dpp_add<0x122>(s);
        s = dpp_add<0x121>(s);
        if (g == 0 && okB) out[oB] = s + base;
      }
      // refill B <- jb+16
      okB = false;
      if (jb + 16 < cend) {
        int e = jb + 16 + q;
        int idx = (e - cb) & 63;
        int sx = __shfl(mx, idx, 64);
        oB = __shfl(my, idx, 64);
        okB = e < cend;
        rBa = *(const u16x8*)(Bb + (size_t)sx * 256);
        rBb = *(const u16x8*)(Bb + (size_t)sx * 256 + 8);
      }
      // consume C
      {
        float s0 = 0.f, s1 = 0.f;
#pragma unroll
        for (int c = 0; c < 8; ++c) s0 += fmaxf(a[c] + bf2f(rCa[c]), 0.f) * w[c];
#pragma unroll
        for (int c = 0; c < 8; ++c) s1 += fmaxf(a[8 + c] + bf2f(rCb[c]), 0.f) * w[8 + c];
        float s = s0 + s1;
        s = dpp_add<0x128>(s);
        s = dpp_add<0x124>(s);
        s = dpp_add<0x122>(s);
        s = dpp_add<0x121>(s);
        if (g == 0 && okC) out[oC] = s + base;
      }
      // refill C <- jb+20
      okC = false;
      if (jb + 20 < cend) {
        int e = jb + 20 + q;
        int idx = (e - cb) & 63;
        int sx = __shfl(mx, idx, 64);
        oC = __shfl(my, idx, 64);
        okC = e < cend;
        rCa = *(const u16x8*)(Bb + (size_t)sx * 256);
        rCb = *(const u16x8*)(Bb + (size_t)sx * 256 + 8);
      }
    }
  }
}

extern "C" void kernel_launch(void* const* d_in, const int* in_sizes, int n_in,
                              void* d_out, int out_size, void* d_ws, size_t ws_size,
                              hipStream_t stream) {
  const float* x      = (const float*)d_in[0];
  const int*   ei     = (const int*)d_in[1];
  const float* attr   = (const float*)d_in[2];
  const int*   ewi    = (const int*)d_in[3];
  const float* p_pool = (const float*)d_in[4];
  const float* W_ih   = (const float*)d_in[5];
  const float* W_hh   = (const float*)d_in[6];
  const float* b_ih   = (const float*)d_in[7];
  const float* b_hh   = (const float*)d_in[8];
  const float* W_init = (const float*)d_in[9];
  const float* lin1_w = (const float*)d_in[10];
  const float* lin1_b = (const float*)d_in[11];
  const float* lin2_w = (const float*)d_in[12];
  const float* lin2_b = (const float*)d_in[13];
  float* out = (float*)d_out;

  const int C = 256;
  const int N = in_sizes[0] / C;   // 50000
  const int E = in_sizes[2];       // 800000

  // ---- workspace layout (256B aligned) ----
  char* ws = (char*)d_ws;
  size_t off = 0;
  auto alloc = [&](size_t bytes) {
    size_t o = off;
    off = (off + bytes + 255) & ~(size_t)255;
    return o;
  };
  float*          score  = (float*)(ws + alloc((size_t)N * 4));
  int*            perm   = (int*)(ws + alloc(C * 4));
  float*          tts    = (float*)(ws + alloc(C * 4));
  unsigned short* WevoT  = (unsigned short*)(ws + alloc((size_t)C * C * 2));
  unsigned short* WAB    = (unsigned short*)(ws + alloc((size_t)2 * C * C * 2));
  // contiguous zero region: ghist | bcnt1 | bcnt2
  int   zeroInts = 4096 + 128 + 128;
  char* zbase    = ws + alloc((size_t)zeroInts * 4);
  int* ghist = (int*)zbase;
  int* bcnt1 = (int*)(zbase + 4096 * 4);
  int* bcnt2 = (int*)(zbase + 4096 * 4 + 128 * 4);
  int*            bbase1 = (int*)(ws + alloc((NBUCK + 1) * 4));
  int*            bbase2 = (int*)(ws + alloc((NBUCK + 1) * 4));
  int*            gcur1  = (int*)(ws + alloc(128 * 4));
  int*            gcur2  = (int*)(ws + alloc(128 * 4));
  float*          dinv   = (float*)(ws + alloc((size_t)N * 4));
  int*            rowp1  = (int*)(ws + alloc((size_t)(N + 1) * 4));
  int*            rowp2  = (int*)(ws + alloc((size_t)(N + 1) * 4));
  int2*           stage1 = (int2*)(ws + alloc((size_t)E * 8));
  int2*           stage2 = (int2*)(ws + alloc((size_t)E * 8));
  int2*           esv    = (int2*)(ws + alloc((size_t)E * 8));
  int2*           eto    = (int2*)(ws + alloc((size_t)E * 8));
  unsigned short* xh     = (unsigned short*)(ws + alloc((size_t)N * C * 2));
  unsigned short* xwh    = (unsigned short*)(ws + alloc((size_t)N * C * 2));
  unsigned short* Bbf    = (unsigned short*)(ws + alloc((size_t)N * C * 2));
  // aliases (stream-ordered producers/consumers):
  unsigned short* ne  = xh;   // xh dead after GEMM1
  unsigned short* Abf = xwh;  // xwh dead after gather

  int nz4 = (zeroInts + 3) / 4;
  int nbP1 = (E + 4095) / 4096;   // 196

  // 1) init: lin1 cast (512 blocks) + zero ghist/bcnt (tail blocks)
  init_kernel<<<512 + (nz4 + 255) / 256, 256, 0, stream>>>(lin1_w, WAB, (int4*)zbase, nz4);

  // 2) score (+||p||) + bf16 cast of x + fused 4096-bin key histogram
  score_cast_kernel<<<(N + 3) / 4, 256, 0, stream>>>(x, p_pool, score, xh, ghist, N);

  // 3) exact top-256: threshold select + collect + bitonic sort
  topk_kernel<<<1, 1024, 0, stream>>>(score, N, C, ghist, perm, tts);

  // 4) GRU (x_tilde inline) -> evolved W (transposed bf16)
  gru_kernel<<<C, C, 0, stream>>>(x, perm, tts, W_init, W_ih, W_hh, b_ih, b_hh, WevoT);

  // 5) xw = x @ Wevo (128x256-tile MFMA, global_load_lds staging)
  mfma_gemm128<<<dim3((N + 127) / 128, 1), 512, 0, stream>>>(xh, WevoT, xwh, xwh, N);

  // 6) CSR build: hist, scan, p1 fused, p2
  bucket_hist_kernel<<<256, 256, 0, stream>>>(ei, ewi, bcnt1, bcnt2, E);
  bucket_scan_kernel<<<1, 128, 0, stream>>>(bcnt1, bcnt2, bbase1, bbase2, gcur1, gcur2,
                                            rowp1, rowp2, N, E);
  p1_both_kernel<<<2 * nbP1, 256, 0, stream>>>(ei, attr, gcur1, stage1,
                                               ewi, gcur2, stage2, E, nbP1);
  p2_kernel<<<2 * NBUCK, 256, 0, stream>>>(stage1, bbase1, esv, rowp1, dinv,
                                           stage2, bbase2, eto, rowp2, N);

  // 7) gather (per-node waves; dinv applied at meta preload)
  gcn_gather<<<(N + 3) / 4, 256, 0, stream>>>(xwh, rowp1, esv, dinv, ne, N);

  // 8) decoder projections: stacked BT (WA^T | WB^T), gridDim.y = 2
  mfma_gemm128<<<dim3((N + 127) / 128, 2), 512, 0, stream>>>(ne, WAB, Abf, Bbf, N);

  // 9) edge decode (per-node waves, 3-stage prefetch + DPP reduce)
  edge_decode_csr<<<(N + 3) / 4, 256, 0, stream>>>(Abf, Bbf, rowp2, eto,
                                                   lin1_b, lin2_w, lin2_b, out, N);
}

// Round 7
// 454.874 us; speedup vs baseline: 1.3272x; 1.3272x over previous
//
#include <hip/hip_runtime.h>
#include <hip/hip_bf16.h>
#include <math.h>

// ---------------------------------------------------------------------------
// EvolveGCNH + GCNConv + EdgeDecoder.
// R1: atomic scatter -> dst-CSR register gather (3574 -> 1223 us).
// R5: parallel top-k, merged CSR builds, dual GEMM (962 us).
// R7: two-phase bucket sort for both CSRs (609 us).
// R8: QUAD decomposition gather/decode + kernel fusion (522 us).
// R11: merged p2 + fused score_cast (510 us).
// R12: DPP reduce in decode, m97-structure GEMMs, 3-stage prefetch (476 us).
// R13/R14: per-chunk meta PRELOAD + shfl broadcast + esv_scale (467 us).
// R15: persistent waves REGRESSED (471): decode/gather are at the ~6.3TB/s
//      gather-path throughput wall (440MB/65us each).
// R17: launch collapse 16->12 REGRESSED (604): folding the score histogram
//      into score_cast as per-wave GLOBAL atomics hit hot-bin serialization
//      (175us @ VALUBusy 4.7%) — the R9 lesson repeated. LDS aggregation is
//      mandatory for concentrated distributions.
// R18 (this round): surgical revert of the hist fusion only — dedicated
//      hist12_kernel (64 blocks, LDS-aggregated) restored. All other R17
//      fusions kept (init=zero+lin1cast, p1 pair fused, dinv at gather
//      meta-preload). 13 launches.
// ---------------------------------------------------------------------------

typedef __attribute__((ext_vector_type(8))) short bf16x8;
typedef __attribute__((ext_vector_type(8))) unsigned short u16x8;
typedef __attribute__((ext_vector_type(4))) float f32x4;

#define WSHIFT 9              // 512 nodes per bucket
#define WMASK 511
#define NBUCK 98              // ceil(50000/512)

__device__ __forceinline__ unsigned f2key(float f) {
  unsigned u = __float_as_uint(f);
  return (u & 0x80000000u) ? ~u : (u | 0x80000000u);
}

// round-to-nearest-even fp32 -> bf16 bits
__device__ __forceinline__ unsigned short f2bf(float f) {
  unsigned u = __float_as_uint(f);
  unsigned r = u + 0x7fffu + ((u >> 16) & 1u);
  return (unsigned short)(r >> 16);
}
__device__ __forceinline__ float bf2f(unsigned short h) {
  return __uint_as_float((unsigned)h << 16);
}

// DPP row-rotate add: sums within each 16-lane row after ror 8,4,2,1.
template <int CTRL>
__device__ __forceinline__ float dpp_add(float s) {
  int t = __builtin_amdgcn_update_dpp(0, __float_as_int(s), CTRL, 0xf, 0xf, false);
  return s + __int_as_float(t);
}

// async global->LDS, 16B per lane; lds ptr must be wave-uniform.
__device__ __forceinline__ void gload16(const void* g, void* l) {
  __builtin_amdgcn_global_load_lds((const __attribute__((address_space(1))) void*)g,
                                   (__attribute__((address_space(3))) void*)l, 16, 0, 0);
}

// blocks 0..511: lin1_w [256][512] -> stacked BT (WA^T rows 0..255, WB^T
// rows 256..511). blocks 512+: zero the ghist|bcnt region.
__global__ __launch_bounds__(256) void init_kernel(const float* __restrict__ lin1,
                                                   unsigned short* __restrict__ WAB,
                                                   int4* __restrict__ zb, int nz4) {
  int b = blockIdx.x, tid = threadIdx.x;
  if (b < 512) {
    int idx = b * 256 + tid;
    int n = idx >> 9, k = idx & 511;
    unsigned short h = f2bf(lin1[idx]);
    if (k < 256)
      WAB[n * 256 + k] = h;
    else
      WAB[(256 + n) * 256 + (k - 256)] = h;
  } else {
    int j = (b - 512) * 256 + tid;
    if (j < nz4) zb[j] = make_int4(0, 0, 0, 0);
  }
}

// score (incl. ||p||) + bf16 cast of x in one pass (x read once)
__global__ __launch_bounds__(256) void score_cast_kernel(const float* __restrict__ x,
                                                         const float* __restrict__ p,
                                                         float* __restrict__ score,
                                                         unsigned short* __restrict__ xh, int N) {
  int node = blockIdx.x * 4 + (threadIdx.x >> 6);
  int lane = threadIdx.x & 63;
  if (node >= N) return;
  float4 xv = ((const float4*)(x + (size_t)node * 256))[lane];
  ushort4 hv;
  hv.x = f2bf(xv.x);
  hv.y = f2bf(xv.y);
  hv.z = f2bf(xv.z);
  hv.w = f2bf(xv.w);
  ((ushort4*)(xh + (size_t)node * 256))[lane] = hv;
  float4 pv = ((const float4*)p)[lane];
  float s = xv.x * pv.x + xv.y * pv.y + xv.z * pv.z + xv.w * pv.w;
  float sp = pv.x * pv.x + pv.y * pv.y + pv.z * pv.z + pv.w * pv.w;
#pragma unroll
  for (int off = 32; off > 0; off >>= 1) {
    s += __shfl_down(s, off, 64);
    sp += __shfl_down(sp, off, 64);
  }
  if (lane == 0) score[node] = s / sqrtf(sp);
}

// grid-wide histogram of the top 12 key bits (4096 bins), LDS-aggregated
// (hot-bin safe: <=64 global adds per bin — R9/R17 lesson).
__global__ __launch_bounds__(256) void hist12_kernel(const float* __restrict__ score, int n,
                                                     int* __restrict__ gh) {
  __shared__ int lh[4096];
  int tid = threadIdx.x;
  for (int i = tid; i < 4096; i += 256) lh[i] = 0;
  __syncthreads();
  int idx = blockIdx.x * 256 + tid;
  int stride = gridDim.x * 256;
  for (int i = idx; i < n; i += stride) {
    unsigned key = f2key(score[i]);
    atomicAdd(&lh[key >> 20], 1);
  }
  __syncthreads();
  for (int i = tid; i < 4096; i += 256) {
    int v = lh[i];
    if (v) atomicAdd(&gh[i], v);
  }
}

// select (suffix-scan over 4096-bin histogram -> bin-floor threshold) fused
// with collect + bitonic sort (key desc, idx asc) -> perm[k], tanh(score).
__global__ __launch_bounds__(1024) void topk_kernel(const float* __restrict__ score, int n, int k,
                                                    const int* __restrict__ gh,
                                                    int* __restrict__ perm,
                                                    float* __restrict__ tts) {
  __shared__ int part[1024];
  __shared__ unsigned sT;
  int tid = threadIdx.x;
  {
    int b0 = tid * 4;
    int s0 = gh[b0], s1 = gh[b0 + 1], s2 = gh[b0 + 2], s3 = gh[b0 + 3];
    part[tid] = s0 + s1 + s2 + s3;
    __syncthreads();
    for (int off = 1; off < 1024; off <<= 1) {
      int v = part[tid];
      int add = (tid + off < 1024) ? part[tid + off] : 0;
      __syncthreads();
      part[tid] = v + add;
      __syncthreads();
    }
    int sufChunk = part[tid];
    int sufNext = (tid < 1023) ? part[tid + 1] : 0;
    if (sufNext < k && sufChunk >= k) {
      int run = sufNext;
      int b;
      run += s3;
      if (run >= k) b = b0 + 3;
      else {
        run += s2;
        if (run >= k) b = b0 + 2;
        else {
          run += s1;
          b = (run >= k) ? b0 + 1 : b0;
        }
      }
      sT = ((unsigned)b) << 20;
    }
  }
  __syncthreads();
  unsigned T = sT;
  __shared__ unsigned keys[1024];
  __shared__ int idxs[1024];
  __shared__ int cnt;
  if (tid == 0) cnt = 0;
  keys[tid] = 0u;
  idxs[tid] = 0x7fffffff;
  __syncthreads();
  for (int i = tid; i < n; i += 1024) {
    unsigned key = f2key(score[i]);
    if (key >= T) {
      int p = atomicAdd(&cnt, 1);
      if (p < 1024) { keys[p] = key; idxs[p] = i; }
    }
  }
  __syncthreads();
  for (int size = 2; size <= 1024; size <<= 1) {
    for (int stride = size >> 1; stride > 0; stride >>= 1) {
      int j = tid ^ stride;
      if (j > tid) {
        unsigned ka = keys[tid], kb = keys[j];
        int ia = idxs[tid], ib = idxs[j];
        bool aBefore = (ka > kb) || (ka == kb && ia < ib);
        bool up = ((tid & size) == 0);
        if (aBefore != up) {
          keys[tid] = kb; keys[j] = ka;
          idxs[tid] = ib; idxs[j] = ia;
        }
      }
      __syncthreads();
    }
  }
  if (tid < k) {
    int idx = idxs[tid];
    perm[tid] = idx;
    tts[tid] = tanhf(score[idx]);
  }
}

// GRU step with x_tilde computed inline (row i = x[perm[i]] * tts[i]);
// writes evolved W TRANSPOSED as bf16: WevoT[n*256 + k] = bf16(W[k][n])
__global__ __launch_bounds__(256) void gru_kernel(const float* __restrict__ x,
                                                  const int* __restrict__ perm,
                                                  const float* __restrict__ tts,
                                                  const float* __restrict__ Wi,
                                                  const float* __restrict__ W_ih,
                                                  const float* __restrict__ W_hh,
                                                  const float* __restrict__ b_ih,
                                                  const float* __restrict__ b_hh,
                                                  unsigned short* __restrict__ WevoT) {
  int i = blockIdx.x, j = threadIdx.x;  // i = k-row of W, j = n-col
  __shared__ float sx[256], sh[256];
  sx[j] = x[(size_t)perm[i] * 256 + j] * tts[i];
  sh[j] = Wi[i * 256 + j];
  __syncthreads();
  float gi[3], gh[3];
#pragma unroll
  for (int g = 0; g < 3; ++g) {
    int row = g * 256 + j;
    const float4* wi4 = (const float4*)(W_ih + (size_t)row * 256);
    const float4* wh4 = (const float4*)(W_hh + (size_t)row * 256);
    float si = 0.f, s2 = 0.f;
    for (int k4 = 0; k4 < 64; ++k4) {
      float4 wv = wi4[k4];
      float4 hv = wh4[k4];
      int k = k4 * 4;
      si += sx[k] * wv.x + sx[k + 1] * wv.y + sx[k + 2] * wv.z + sx[k + 3] * wv.w;
      s2 += sh[k] * hv.x + sh[k + 1] * hv.y + sh[k + 2] * hv.z + sh[k + 3] * hv.w;
    }
    gi[g] = si + b_ih[row];
    gh[g] = s2 + b_hh[row];
  }
  float r = 1.f / (1.f + expf(-(gi[0] + gh[0])));
  float z = 1.f / (1.f + expf(-(gi[1] + gh[1])));
  float nn = tanhf(gi[2] + r * gh[2]);
  float w = (1.f - z) * nn + z * sh[j];
  WevoT[(size_t)j * 256 + i] = f2bf(w);
}

// ---------------------------------------------------------------------------
// m97-structure bf16 MFMA GEMM: per blockIdx.y,
//   C[M,256] = A[M,256] @ (BT[by*256 .. by*256+255][256])^T   (bf16 in/out)
// 128x256 tile, 8 waves (2 wm x 4 wn), BK=32, global_load_lds staging,
// 2-barrier K-loop. Rows >= M read in-workspace garbage (never written back).
// ---------------------------------------------------------------------------
__global__ __launch_bounds__(512) void mfma_gemm128(const unsigned short* __restrict__ A,
                                                    const unsigned short* __restrict__ BT,
                                                    unsigned short* __restrict__ C1,
                                                    unsigned short* __restrict__ C2,
                                                    int M) {
  __shared__ unsigned short sA[128 * 32];
  __shared__ unsigned short sB[256 * 32];
  int tid = threadIdx.x;
  int wave = tid >> 6, lane = tid & 63;
  int quad = lane >> 4, r16 = lane & 15;
  int wm = wave >> 2, wn = wave & 3;
  int mbase = blockIdx.x * 128;
  const unsigned short* Bt = BT + ((size_t)blockIdx.y << 16);
  unsigned short* Cout = blockIdx.y ? C2 : C1;

  // staging map: thread t stages 16B -> LDS byte t*16 (= row t>>2, colq t&3)
  int srow = tid >> 2, scolq = tid & 3;
  const unsigned short* gA = A + (size_t)(mbase + srow) * 256 + scolq * 8;
  const unsigned short* gB0 = Bt + (size_t)srow * 256 + scolq * 8;
  const unsigned short* gB1 = Bt + (size_t)(128 + srow) * 256 + scolq * 8;
  unsigned short* lA = sA + wave * 512;          // wave-uniform LDS bases
  unsigned short* lB0 = sB + wave * 512;
  unsigned short* lB1 = sB + 4096 + wave * 512;

  f32x4 acc[4][4];
#pragma unroll
  for (int i = 0; i < 4; ++i)
#pragma unroll
    for (int j = 0; j < 4; ++j) acc[i][j] = (f32x4){0.f, 0.f, 0.f, 0.f};

  const unsigned short* pA = sA + (wm * 64 + r16) * 32 + quad * 8;
  const unsigned short* pB = sB + (wn * 64 + r16) * 32 + quad * 8;

  for (int k0 = 0; k0 < 256; k0 += 32) {
    if (k0) __syncthreads();              // prior compute done before overwrite
    gload16(gA + k0, lA);
    gload16(gB0 + k0, lB0);
    gload16(gB1 + k0, lB1);
    __syncthreads();                      // drains vmcnt -> staging complete
    bf16x8 af[4], bfr[4];
#pragma unroll
    for (int mt = 0; mt < 4; ++mt) af[mt] = *(const bf16x8*)(pA + mt * 512);
#pragma unroll
    for (int nt = 0; nt < 4; ++nt) bfr[nt] = *(const bf16x8*)(pB + nt * 512);
#pragma unroll
    for (int mt = 0; mt < 4; ++mt)
#pragma unroll
      for (int nt = 0; nt < 4; ++nt)
        acc[mt][nt] = __builtin_amdgcn_mfma_f32_16x16x32_bf16(af[mt], bfr[nt], acc[mt][nt], 0, 0, 0);
  }
#pragma unroll
  for (int mt = 0; mt < 4; ++mt) {
#pragma unroll
    for (int rr = 0; rr < 4; ++rr) {
      int grow = mbase + wm * 64 + mt * 16 + quad * 4 + rr;
      if (grow < M) {
#pragma unroll
        for (int nt = 0; nt < 4; ++nt)
          Cout[(size_t)grow * 256 + wn * 64 + nt * 16 + r16] = f2bf(acc[mt][nt][rr]);
      }
    }
  }
}

// ---- two-phase bucket sort for both CSRs (98 buckets, 512 nodes each) ------

// phase 0: bucket histogram for conv-dst and decoder-src (LDS-aggregated)
__global__ __launch_bounds__(256) void bucket_hist_kernel(const int* __restrict__ ei,
                                                          const int* __restrict__ ewi,
                                                          int* __restrict__ bcnt1,
                                                          int* __restrict__ bcnt2, int E) {
  __shared__ int c1[128], c2[128];
  int tid = threadIdx.x;
  if (tid < 128) { c1[tid] = 0; c2[tid] = 0; }
  __syncthreads();
  int idx = blockIdx.x * 256 + tid;
  int stride = gridDim.x * 256;
  for (int e = idx; e < E; e += stride) {
    atomicAdd(&c1[ei[E + e] >> WSHIFT], 1);
    atomicAdd(&c2[ewi[e] >> WSHIFT], 1);
  }
  __syncthreads();
  if (tid < 128) {
    if (c1[tid]) atomicAdd(&bcnt1[tid], c1[tid]);
    if (c2[tid]) atomicAdd(&bcnt2[tid], c2[tid]);
  }
}

// phase 0b: scan bucket counts -> bases + cursors; also rowp[N] = E
__global__ __launch_bounds__(128) void bucket_scan_kernel(const int* __restrict__ bcnt1,
                                                          const int* __restrict__ bcnt2,
                                                          int* __restrict__ bbase1,
                                                          int* __restrict__ bbase2,
                                                          int* __restrict__ gcur1,
                                                          int* __restrict__ gcur2,
                                                          int* __restrict__ rowp1,
                                                          int* __restrict__ rowp2, int N, int E) {
  __shared__ int ss[128];
  int tid = threadIdx.x;
  // CSR 1
  int v = (tid < NBUCK) ? bcnt1[tid] : 0;
  ss[tid] = v;
  __syncthreads();
  for (int off = 1; off < 128; off <<= 1) {
    int a = ss[tid];
    int b = (tid >= off) ? ss[tid - off] : 0;
    __syncthreads();
    ss[tid] = a + b;
    __syncthreads();
  }
  int excl = ss[tid] - v;
  if (tid < NBUCK) { bbase1[tid] = excl; gcur1[tid] = excl; }
  if (tid == NBUCK - 1) bbase1[NBUCK] = excl + v;
  __syncthreads();
  // CSR 2
  v = (tid < NBUCK) ? bcnt2[tid] : 0;
  ss[tid] = v;
  __syncthreads();
  for (int off = 1; off < 128; off <<= 1) {
    int a = ss[tid];
    int b = (tid >= off) ? ss[tid - off] : 0;
    __syncthreads();
    ss[tid] = a + b;
    __syncthreads();
  }
  excl = ss[tid] - v;
  if (tid < NBUCK) { bbase2[tid] = excl; gcur2[tid] = excl; }
  if (tid == NBUCK - 1) bbase2[NBUCK] = excl + v;
  if (tid == 0) { rowp1[N] = E; rowp2[N] = E; }
}

// phase 1 fused (conv blocks [0,nb), decoder blocks [nb,2nb)): tile-ranked
// scatter into bucket staging, 4096 edges/block.
// conv:  stage.x = src | (dstLocal<<16), stage.y = attr bits
// dec:   stage.x = dst | (srcLocal<<16), stage.y = edge_id
__global__ __launch_bounds__(256) void p1_both_kernel(const int* __restrict__ ei,
                                                      const float* __restrict__ attr,
                                                      int* __restrict__ gcur1,
                                                      int2* __restrict__ stage1,
                                                      const int* __restrict__ ewi,
                                                      int* __restrict__ gcur2,
                                                      int2* __restrict__ stage2,
                                                      int E, int nb) {
  __shared__ int cnt[128], cur[128];
  int tid = threadIdx.x;
  bool conv = blockIdx.x < nb;
  int base = (conv ? blockIdx.x : blockIdx.x - nb) * 4096;
  int* gcur = conv ? gcur1 : gcur2;
  int2* stage = conv ? stage1 : stage2;
  if (tid < 128) cnt[tid] = 0;
  __syncthreads();
  int bk[16];
  int2 pl[16];
#pragma unroll
  for (int i = 0; i < 16; ++i) {
    int e = base + i * 256 + tid;
    bk[i] = -1;
    if (e < E) {
      if (conv) {
        int d = ei[E + e];
        int s = ei[e];
        bk[i] = d >> WSHIFT;
        pl[i] = make_int2(s | ((d & WMASK) << 16), __float_as_int(attr[e]));
      } else {
        int s = ewi[e];
        int d = ewi[E + e];
        bk[i] = s >> WSHIFT;
        pl[i] = make_int2(d | ((s & WMASK) << 16), e);
      }
      atomicAdd(&cnt[bk[i]], 1);
    }
  }
  __syncthreads();
  if (tid < NBUCK) {
    int c = cnt[tid];
    cur[tid] = c ? atomicAdd(&gcur[tid], c) : 0;
  }
  __syncthreads();
#pragma unroll
  for (int i = 0; i < 16; ++i) {
    if (bk[i] >= 0) {
      int pos = atomicAdd(&cur[bk[i]], 1);
      stage[pos] = pl[i];
    }
  }
}

// phase 2 (both CSRs, gridDim.x = 2*NBUCK = 196): one block per bucket.
// LDS 512-bin node histogram (+deg for conv), scan, node-ordered CSR write.
__global__ __launch_bounds__(256) void p2_kernel(const int2* __restrict__ stage1,
                                                 const int* __restrict__ bbase1,
                                                 int2* __restrict__ esv,
                                                 int* __restrict__ rowp1,
                                                 float* __restrict__ dinv,
                                                 const int2* __restrict__ stage2,
                                                 const int* __restrict__ bbase2,
                                                 int2* __restrict__ eto,
                                                 int* __restrict__ rowp2, int N) {
  __shared__ int cnt[512];
  __shared__ float degs[512];
  __shared__ int pref[512];
  __shared__ int ss[256];
  int tid = threadIdx.x;
  bool isConv = blockIdx.x < NBUCK;
  int b = isConv ? blockIdx.x : blockIdx.x - NBUCK;
  const int2* stage = isConv ? stage1 : stage2;
  const int* bbase = isConv ? bbase1 : bbase2;
  int beg = bbase[b], end = bbase[b + 1];
  int node0 = b << WSHIFT;
  cnt[tid] = 0; cnt[tid + 256] = 0;
  degs[tid] = 0.f; degs[tid + 256] = 0.f;
  __syncthreads();
  for (int j = beg + tid; j < end; j += 256) {
    int2 p = stage[j];
    int loc = p.x >> 16;
    atomicAdd(&cnt[loc], 1);
    if (isConv) atomicAdd(&degs[loc], __int_as_float(p.y));
  }
  __syncthreads();
  // exclusive scan over 512 bins (each thread owns 2 consecutive)
  int c0 = cnt[2 * tid], c1 = cnt[2 * tid + 1];
  ss[tid] = c0 + c1;
  __syncthreads();
  for (int off = 1; off < 256; off <<= 1) {
    int a = ss[tid];
    int bb = (tid >= off) ? ss[tid - off] : 0;
    __syncthreads();
    ss[tid] = a + bb;
    __syncthreads();
  }
  int excl = (tid ? ss[tid - 1] : 0);
  pref[2 * tid] = excl;
  pref[2 * tid + 1] = excl + c0;
  __syncthreads();
#pragma unroll
  for (int h = 0; h < 2; ++h) {
    int i = tid + h * 256;
    int node = node0 + i;
    if (node < N) {
      if (isConv) {
        rowp1[node] = beg + pref[i];
        float d = degs[i];
        dinv[node] = d > 0.f ? 1.f / sqrtf(d) : 0.f;
      } else {
        rowp2[node] = beg + pref[i];
      }
    }
  }
  __syncthreads();
  int2* outb = isConv ? esv : eto;
  for (int j = beg + tid; j < end; j += 256) {
    int2 p = stage[j];
    int loc = p.x >> 16;
    int pos = beg + atomicAdd(&pref[loc], 1);
    outb[pos] = make_int2(p.x & 0xFFFF, p.y);
  }
}

// one wave per dst node, quad decomposition: 16 lanes/edge x 4 edges/group.
// Per 64-edge chunk: lane l coalesced-loads meta esv[cb+l] and applies
// dinv[src] once (L2-resident), then stage refills broadcast src/v via shfl
// (refill chain rows-only). 3-stage in-place prefetch.
__global__ __launch_bounds__(256) void gcn_gather(const unsigned short* __restrict__ xw,
                                                  const int* __restrict__ row_ptr,
                                                  const int2* __restrict__ esv,
                                                  const float* __restrict__ dinv,
                                                  unsigned short* __restrict__ ne, int N) {
  int node = blockIdx.x * 4 + (threadIdx.x >> 6);
  int lane = threadIdx.x & 63;
  int g = lane & 15, q = lane >> 4;
  if (node >= N) return;
  int beg = row_ptr[node], end = row_ptr[node + 1];
  float acc[16];
#pragma unroll
  for (int c = 0; c < 16; ++c) acc[c] = 0.f;
  const unsigned short* xb = xw + g * 16;

  for (int cb = beg; cb < end; cb += 64) {
    int cend = cb + 64 < end ? cb + 64 : end;
    int me = cb + lane;
    int2 mm = (me < cend) ? esv[me] : make_int2(0, 0);
    int mx = mm.x;
    float mv = __int_as_float(mm.y) * dinv[mx];

    float vA = 0.f, vB = 0.f, vC = 0.f;
    u16x8 rAa, rAb, rBa, rBb, rCa, rCb;
    {
      int e = cb + q;
      int sx = __shfl(mx, q, 64);
      float tv = __shfl(mv, q, 64);
      vA = (e < cend) ? tv : 0.f;
      rAa = *(const u16x8*)(xb + (size_t)sx * 256);
      rAb = *(const u16x8*)(xb + (size_t)sx * 256 + 8);
    }
    if (cb + 4 < cend) {
      int e = cb + 4 + q;
      int sx = __shfl(mx, 4 + q, 64);
      float tv = __shfl(mv, 4 + q, 64);
      vB = (e < cend) ? tv : 0.f;
      rBa = *(const u16x8*)(xb + (size_t)sx * 256);
      rBb = *(const u16x8*)(xb + (size_t)sx * 256 + 8);
    } else { rBa = rAa; rBb = rAb; }
    if (cb + 8 < cend) {
      int e = cb + 8 + q;
      int sx = __shfl(mx, 8 + q, 64);
      float tv = __shfl(mv, 8 + q, 64);
      vC = (e < cend) ? tv : 0.f;
      rCa = *(const u16x8*)(xb + (size_t)sx * 256);
      rCb = *(const u16x8*)(xb + (size_t)sx * 256 + 8);
    } else { rCa = rAa; rCb = rAb; }

    for (int jb = cb; jb < cend; jb += 12) {
      // consume A, refill A <- jb+12
#pragma unroll
      for (int c = 0; c < 8; ++c) acc[c] += bf2f(rAa[c]) * vA;
#pragma unroll
      for (int c = 0; c < 8; ++c) acc[8 + c] += bf2f(rAb[c]) * vA;
      vA = 0.f;
      if (jb + 12 < cend) {
        int e = jb + 12 + q;
        int idx = (e - cb) & 63;
        int sx = __shfl(mx, idx, 64);
        float tv = __shfl(mv, idx, 64);
        vA = (e < cend) ? tv : 0.f;
        rAa = *(const u16x8*)(xb + (size_t)sx * 256);
        rAb = *(const u16x8*)(xb + (size_t)sx * 256 + 8);
      }
      // consume B, refill B <- jb+16
#pragma unroll
      for (int c = 0; c < 8; ++c) acc[c] += bf2f(rBa[c]) * vB;
#pragma unroll
      for (int c = 0; c < 8; ++c) acc[8 + c] += bf2f(rBb[c]) * vB;
      vB = 0.f;
      if (jb + 16 < cend) {
        int e = jb + 16 + q;
        int idx = (e - cb) & 63;
        int sx = __shfl(mx, idx, 64);
        float tv = __shfl(mv, idx, 64);
        vB = (e < cend) ? tv : 0.f;
        rBa = *(const u16x8*)(xb + (size_t)sx * 256);
        rBb = *(const u16x8*)(xb + (size_t)sx * 256 + 8);
      }
      // consume C, refill C <- jb+20
#pragma unroll
      for (int c = 0; c < 8; ++c) acc[c] += bf2f(rCa[c]) * vC;
#pragma unroll
      for (int c = 0; c < 8; ++c) acc[8 + c] += bf2f(rCb[c]) * vC;
      vC = 0.f;
      if (jb + 20 < cend) {
        int e = jb + 20 + q;
        int idx = (e - cb) & 63;
        int sx = __shfl(mx, idx, 64);
        float tv = __shfl(mv, idx, 64);
        vC = (e < cend) ? tv : 0.f;
        rCa = *(const u16x8*)(xb + (size_t)sx * 256);
        rCb = *(const u16x8*)(xb + (size_t)sx * 256 + 8);
      }
    }
  }
  // cross-quad combine (each quad holds a partial over the same channels)
#pragma unroll
  for (int c = 0; c < 16; ++c) {
    acc[c] += __shfl_xor(acc[c], 16, 64);
    acc[c] += __shfl_xor(acc[c], 32, 64);
  }
  if (q == 0) {
    float dd = dinv[node];
    u16x8 o0, o1;
#pragma unroll
    for (int c = 0; c < 8; ++c) {
      o0[c] = f2bf(acc[c] * dd);
      o1[c] = f2bf(acc[8 + c] * dd);
    }
    *(u16x8*)(ne + (size_t)node * 256 + g * 16) = o0;
    *(u16x8*)(ne + (size_t)node * 256 + g * 16 + 8) = o1;
  }
}

// decode grouped by src, one wave per node, quad decomposition. Per-chunk
// meta preload + shfl broadcast; 3-stage in-place prefetch; DPP row_ror
// reduce. A[s]+b1 and w2 register-resident per lane (16 channels).
__global__ __launch_bounds__(256) void edge_decode_csr(const unsigned short* __restrict__ A,
                                                       const unsigned short* __restrict__ Bm,
                                                       const int* __restrict__ row_ptr,
                                                       const int2* __restrict__ eto,
                                                       const float* __restrict__ b1,
                                                       const float* __restrict__ w2,
                                                       const float* __restrict__ b2,
                                                       float* __restrict__ out, int N) {
  int node = blockIdx.x * 4 + (threadIdx.x >> 6);
  int lane = threadIdx.x & 63;
  int g = lane & 15, q = lane >> 4;
  if (node >= N) return;
  int beg = row_ptr[node], end = row_ptr[node + 1];
  if (beg >= end) return;
  float a[16], w[16];
  {
    u16x8 a0 = *(const u16x8*)(A + (size_t)node * 256 + g * 16);
    u16x8 a1 = *(const u16x8*)(A + (size_t)node * 256 + g * 16 + 8);
    const float4* bp = (const float4*)(b1 + g * 16);
    const float4* wp = (const float4*)(w2 + g * 16);
#pragma unroll
    for (int i = 0; i < 4; ++i) {
      float4 bv = bp[i];
      float4 wv = wp[i];
      a[i * 4 + 0] = (i < 2 ? bf2f(a0[i * 4 + 0]) : bf2f(a1[i * 4 - 8])) + bv.x;
      a[i * 4 + 1] = (i < 2 ? bf2f(a0[i * 4 + 1]) : bf2f(a1[i * 4 - 7])) + bv.y;
      a[i * 4 + 2] = (i < 2 ? bf2f(a0[i * 4 + 2]) : bf2f(a1[i * 4 - 6])) + bv.z;
      a[i * 4 + 3] = (i < 2 ? bf2f(a0[i * 4 + 3]) : bf2f(a1[i * 4 - 5])) + bv.w;
      w[i * 4 + 0] = wv.x;
      w[i * 4 + 1] = wv.y;
      w[i * 4 + 2] = wv.z;
      w[i * 4 + 3] = wv.w;
    }
  }
  float base = b2[0];
  const unsigned short* Bb = Bm + g * 16;

  for (int cb = beg; cb < end; cb += 64) {
    int cend = cb + 64 < end ? cb + 64 : end;
    int me = cb + lane;
    int2 mm = (me < cend) ? eto[me] : make_int2(0, 0);
    int mx = mm.x, my = mm.y;

    bool okA = false, okB = false, okC = false;
    int oA = 0, oB = 0, oC = 0;
    u16x8 rAa, rAb, rBa, rBb, rCa, rCb;
    {
      int e = cb + q;
      int sx = __shfl(mx, q, 64);
      oA = __shfl(my, q, 64);
      okA = e < cend;
      rAa = *(const u16x8*)(Bb + (size_t)sx * 256);
      rAb = *(const u16x8*)(Bb + (size_t)sx * 256 + 8);
    }
    if (cb + 4 < cend) {
      int e = cb + 4 + q;
      int sx = __shfl(mx, 4 + q, 64);
      oB = __shfl(my, 4 + q, 64);
      okB = e < cend;
      rBa = *(const u16x8*)(Bb + (size_t)sx * 256);
      rBb = *(const u16x8*)(Bb + (size_t)sx * 256 + 8);
    } else { rBa = rAa; rBb = rAb; }
    if (cb + 8 < cend) {
      int e = cb + 8 + q;
      int sx = __shfl(mx, 8 + q, 64);
      oC = __shfl(my, 8 + q, 64);
      okC = e < cend;
      rCa = *(const u16x8*)(Bb + (size_t)sx * 256);
      rCb = *(const u16x8*)(Bb + (size_t)sx * 256 + 8);
    } else { rCa = rAa; rCb = rAb; }

    for (int jb = cb; jb < cend; jb += 12) {
      // consume A
      {
        float s0 = 0.f, s1 = 0.f;
#pragma unroll
        for (int c = 0; c < 8; ++c) s0 += fmaxf(a[c] + bf2f(rAa[c]), 0.f) * w[c];
#pragma unroll
        for (int c = 0; c < 8; ++c) s1 += fmaxf(a[8 + c] + bf2f(rAb[c]), 0.f) * w[8 + c];
        float s = s0 + s1;
        s = dpp_add<0x128>(s);  // row_ror:8
        s = dpp_add<0x124>(s);  // row_ror:4
        s = dpp_add<0x122>(s);  // row_ror:2
        s = dpp_add<0x121>(s);  // row_ror:1
        if (g == 0 && okA) out[oA] = s + base;
      }
      // refill A <- jb+12
      okA = false;
      if (jb + 12 < cend) {
        int e = jb + 12 + q;
        int idx = (e - cb) & 63;
        int sx = __shfl(mx, idx, 64);
        oA = __shfl(my, idx, 64);
        okA = e < cend;
        rAa = *(const u16x8*)(Bb + (size_t)sx * 256);
        rAb = *(const u16x8*)(Bb + (size_t)sx * 256 + 8);
      }
      // consume B
      {
        float s0 = 0.f, s1 = 0.f;
#pragma unroll
        for (int c = 0; c < 8; ++c) s0 += fmaxf(a[c] + bf2f(rBa[c]), 0.f) * w[c];
#pragma unroll
        for (int c = 0; c < 8; ++c) s1 += fmaxf(a[8 + c] + bf2f(rBb[c]), 0.f) * w[8 + c];
        float s = s0 + s1;
        s = dpp_add<0x128>(s);
        s = dpp_add<0x124>(s);
        s = dpp_add<0x122>(s);
        s = dpp_add<0x121>(s);
        if (g == 0 && okB) out[oB] = s + base;
      }
      // refill B <- jb+16
      okB = false;
      if (jb + 16 < cend) {
        int e = jb + 16 + q;
        int idx = (e - cb) & 63;
        int sx = __shfl(mx, idx, 64);
        oB = __shfl(my, idx, 64);
        okB = e < cend;
        rBa = *(const u16x8*)(Bb + (size_t)sx * 256);
        rBb = *(const u16x8*)(Bb + (size_t)sx * 256 + 8);
      }
      // consume C
      {
        float s0 = 0.f, s1 = 0.f;
#pragma unroll
        for (int c = 0; c < 8; ++c) s0 += fmaxf(a[c] + bf2f(rCa[c]), 0.f) * w[c];
#pragma unroll
        for (int c = 0; c < 8; ++c) s1 += fmaxf(a[8 + c] + bf2f(rCb[c]), 0.f) * w[8 + c];
        float s = s0 + s1;
        s = dpp_add<0x128>(s);
        s = dpp_add<0x124>(s);
        s = dpp_add<0x122>(s);
        s = dpp_add<0x121>(s);
        if (g == 0 && okC) out[oC] = s + base;
      }
      // refill C <- jb+20
      okC = false;
      if (jb + 20 < cend) {
        int e = jb + 20 + q;
        int idx = (e - cb) & 63;
        int sx = __shfl(mx, idx, 64);
        oC = __shfl(my, idx, 64);
        okC = e < cend;
        rCa = *(const u16x8*)(Bb + (size_t)sx * 256);
        rCb = *(const u16x8*)(Bb + (size_t)sx * 256 + 8);
      }
    }
  }
}

extern "C" void kernel_launch(void* const* d_in, const int* in_sizes, int n_in,
                              void* d_out, int out_size, void* d_ws, size_t ws_size,
                              hipStream_t stream) {
  const float* x      = (const float*)d_in[0];
  const int*   ei     = (const int*)d_in[1];
  const float* attr   = (const float*)d_in[2];
  const int*   ewi    = (const int*)d_in[3];
  const float* p_pool = (const float*)d_in[4];
  const float* W_ih   = (const float*)d_in[5];
  const float* W_hh   = (const float*)d_in[6];
  const float* b_ih   = (const float*)d_in[7];
  const float* b_hh   = (const float*)d_in[8];
  const float* W_init = (const float*)d_in[9];
  const float* lin1_w = (const float*)d_in[10];
  const float* lin1_b = (const float*)d_in[11];
  const float* lin2_w = (const float*)d_in[12];
  const float* lin2_b = (const float*)d_in[13];
  float* out = (float*)d_out;

  const int C = 256;
  const int N = in_sizes[0] / C;   // 50000
  const int E = in_sizes[2];       // 800000

  // ---- workspace layout (256B aligned) ----
  char* ws = (char*)d_ws;
  size_t off = 0;
  auto alloc = [&](size_t bytes) {
    size_t o = off;
    off = (off + bytes + 255) & ~(size_t)255;
    return o;
  };
  float*          score  = (float*)(ws + alloc((size_t)N * 4));
  int*            perm   = (int*)(ws + alloc(C * 4));
  float*          tts    = (float*)(ws + alloc(C * 4));
  unsigned short* WevoT  = (unsigned short*)(ws + alloc((size_t)C * C * 2));
  unsigned short* WAB    = (unsigned short*)(ws + alloc((size_t)2 * C * C * 2));
  // contiguous zero region: ghist | bcnt1 | bcnt2
  int   zeroInts = 4096 + 128 + 128;
  char* zbase    = ws + alloc((size_t)zeroInts * 4);
  int* ghist = (int*)zbase;
  int* bcnt1 = (int*)(zbase + 4096 * 4);
  int* bcnt2 = (int*)(zbase + 4096 * 4 + 128 * 4);
  int*            bbase1 = (int*)(ws + alloc((NBUCK + 1) * 4));
  int*            bbase2 = (int*)(ws + alloc((NBUCK + 1) * 4));
  int*            gcur1  = (int*)(ws + alloc(128 * 4));
  int*            gcur2  = (int*)(ws + alloc(128 * 4));
  float*          dinv   = (float*)(ws + alloc((size_t)N * 4));
  int*            rowp1  = (int*)(ws + alloc((size_t)(N + 1) * 4));
  int*            rowp2  = (int*)(ws + alloc((size_t)(N + 1) * 4));
  int2*           stage1 = (int2*)(ws + alloc((size_t)E * 8));
  int2*           stage2 = (int2*)(ws + alloc((size_t)E * 8));
  int2*           esv    = (int2*)(ws + alloc((size_t)E * 8));
  int2*           eto    = (int2*)(ws + alloc((size_t)E * 8));
  unsigned short* xh     = (unsigned short*)(ws + alloc((size_t)N * C * 2));
  unsigned short* xwh    = (unsigned short*)(ws + alloc((size_t)N * C * 2));
  unsigned short* Bbf    = (unsigned short*)(ws + alloc((size_t)N * C * 2));
  // aliases (stream-ordered producers/consumers):
  unsigned short* ne  = xh;   // xh dead after GEMM1
  unsigned short* Abf = xwh;  // xwh dead after gather

  int nz4 = (zeroInts + 3) / 4;
  int nbP1 = (E + 4095) / 4096;   // 196

  // 1) init: lin1 cast (512 blocks) + zero ghist/bcnt (tail blocks)
  init_kernel<<<512 + (nz4 + 255) / 256, 256, 0, stream>>>(lin1_w, WAB, (int4*)zbase, nz4);

  // 2) score (+||p||) + bf16 cast of x
  score_cast_kernel<<<(N + 3) / 4, 256, 0, stream>>>(x, p_pool, score, xh, N);

  // 3) LDS-aggregated 4096-bin histogram + exact top-256
  hist12_kernel<<<64, 256, 0, stream>>>(score, N, ghist);
  topk_kernel<<<1, 1024, 0, stream>>>(score, N, C, ghist, perm, tts);

  // 4) GRU (x_tilde inline) -> evolved W (transposed bf16)
  gru_kernel<<<C, C, 0, stream>>>(x, perm, tts, W_init, W_ih, W_hh, b_ih, b_hh, WevoT);

  // 5) xw = x @ Wevo (128x256-tile MFMA, global_load_lds staging)
  mfma_gemm128<<<dim3((N + 127) / 128, 1), 512, 0, stream>>>(xh, WevoT, xwh, xwh, N);

  // 6) CSR build: hist, scan, p1 fused, p2
  bucket_hist_kernel<<<256, 256, 0, stream>>>(ei, ewi, bcnt1, bcnt2, E);
  bucket_scan_kernel<<<1, 128, 0, stream>>>(bcnt1, bcnt2, bbase1, bbase2, gcur1, gcur2,
                                            rowp1, rowp2, N, E);
  p1_both_kernel<<<2 * nbP1, 256, 0, stream>>>(ei, attr, gcur1, stage1,
                                               ewi, gcur2, stage2, E, nbP1);
  p2_kernel<<<2 * NBUCK, 256, 0, stream>>>(stage1, bbase1, esv, rowp1, dinv,
                                           stage2, bbase2, eto, rowp2, N);

  // 7) gather (per-node waves; dinv applied at meta preload)
  gcn_gather<<<(N + 3) / 4, 256, 0, stream>>>(xwh, rowp1, esv, dinv, ne, N);

  // 8) decoder projections: stacked BT (WA^T | WB^T), gridDim.y = 2
  mfma_gemm128<<<dim3((N + 127) / 128, 2), 512, 0, stream>>>(ne, WAB, Abf, Bbf, N);

  // 9) edge decode (per-node waves, 3-stage prefetch + DPP reduce)
  edge_decode_csr<<<(N + 3) / 4, 256, 0, stream>>>(Abf, Bbf, rowp2, eto,
                                                   lin1_b, lin2_w, lin2_b, out, N);
}

// Round 8
// 405.643 us; speedup vs baseline: 1.4883x; 1.1214x over previous
//
#include <hip/hip_runtime.h>
#include <hip/hip_bf16.h>
#include <math.h>

// ---------------------------------------------------------------------------
// EvolveGCNH + GCNConv + EdgeDecoder.
// R1: atomic scatter -> dst-CSR register gather (3574 -> 1223 us).
// R7: two-phase bucket sort for both CSRs (609 us).
// R8: QUAD decomposition gather/decode + kernel fusion (522 us).
// R12: DPP reduce in decode, m97-structure GEMMs, 3-stage prefetch (476 us).
// R13/R14: per-chunk meta PRELOAD + shfl broadcast (467 us).
// R15: persistent waves REGRESSED: decode/gather sit at the gather-path
//      throughput wall (~440MB logical / ~68us each); latency knobs done.
// R17: global-atomic score hist REGRESSED (604) — hot-bin serialization;
//      LDS aggregation mandatory (R9 lesson).
// R18: launch collapse w/ LDS hist12 restored: 455 us (best). Decode 68 at
//      its plateau; ~170us of the total remains in the unprofiled middle.
// R19 (this round): CO-LAUNCH the two independent chains (pool chain:
//      score->hist12->topk->gru; CSR chain: bhist->bscan->p1->p2) as
//      block-range-split fused kernels:
//        A: bucket_hist || score_cast     B: hist12 || bucket_scan
//        C: topk || p1 (1024 thr, 8 e/t)  D: gru || p2
//      Hides the 1-block serial kernels under wide CSR work; 13->9 launches.
//      All kernel INTERNALS unchanged from R18.
// ---------------------------------------------------------------------------

typedef __attribute__((ext_vector_type(8))) short bf16x8;
typedef __attribute__((ext_vector_type(8))) unsigned short u16x8;
typedef __attribute__((ext_vector_type(4))) float f32x4;

#define WSHIFT 9              // 512 nodes per bucket
#define WMASK 511
#define NBUCK 98              // ceil(50000/512)

__device__ __forceinline__ unsigned f2key(float f) {
  unsigned u = __float_as_uint(f);
  return (u & 0x80000000u) ? ~u : (u | 0x80000000u);
}

// round-to-nearest-even fp32 -> bf16 bits
__device__ __forceinline__ unsigned short f2bf(float f) {
  unsigned u = __float_as_uint(f);
  unsigned r = u + 0x7fffu + ((u >> 16) & 1u);
  return (unsigned short)(r >> 16);
}
__device__ __forceinline__ float bf2f(unsigned short h) {
  return __uint_as_float((unsigned)h << 16);
}

// DPP row-rotate add: sums within each 16-lane row after ror 8,4,2,1.
template <int CTRL>
__device__ __forceinline__ float dpp_add(float s) {
  int t = __builtin_amdgcn_update_dpp(0, __float_as_int(s), CTRL, 0xf, 0xf, false);
  return s + __int_as_float(t);
}

// async global->LDS, 16B per lane; lds ptr must be wave-uniform.
__device__ __forceinline__ void gload16(const void* g, void* l) {
  __builtin_amdgcn_global_load_lds((const __attribute__((address_space(1))) void*)g,
                                   (__attribute__((address_space(3))) void*)l, 16, 0, 0);
}

// blocks 0..511: lin1_w [256][512] -> stacked BT (WA^T rows 0..255, WB^T
// rows 256..511). blocks 512+: zero the ghist|bcnt region.
__global__ __launch_bounds__(256) void init_kernel(const float* __restrict__ lin1,
                                                   unsigned short* __restrict__ WAB,
                                                   int4* __restrict__ zb, int nz4) {
  int b = blockIdx.x, tid = threadIdx.x;
  if (b < 512) {
    int idx = b * 256 + tid;
    int n = idx >> 9, k = idx & 511;
    unsigned short h = f2bf(lin1[idx]);
    if (k < 256)
      WAB[n * 256 + k] = h;
    else
      WAB[(256 + n) * 256 + (k - 256)] = h;
  } else {
    int j = (b - 512) * 256 + tid;
    if (j < nz4) zb[j] = make_int4(0, 0, 0, 0);
  }
}

// ---------------- fused A: bucket_hist (blocks 0..255) || score_cast -------
__global__ __launch_bounds__(256) void fusedA_kernel(const float* __restrict__ x,
                                                     const float* __restrict__ p,
                                                     float* __restrict__ score,
                                                     unsigned short* __restrict__ xh, int N,
                                                     const int* __restrict__ ei,
                                                     const int* __restrict__ ewi,
                                                     int* __restrict__ bcnt1,
                                                     int* __restrict__ bcnt2, int E) {
  int tid = threadIdx.x;
  if (blockIdx.x < 256) {
    // bucket histogram for conv-dst and decoder-src (LDS-aggregated)
    __shared__ int c1[128], c2[128];
    if (tid < 128) { c1[tid] = 0; c2[tid] = 0; }
    __syncthreads();
    int idx = blockIdx.x * 256 + tid;
    int stride = 256 * 256;
    for (int e = idx; e < E; e += stride) {
      atomicAdd(&c1[ei[E + e] >> WSHIFT], 1);
      atomicAdd(&c2[ewi[e] >> WSHIFT], 1);
    }
    __syncthreads();
    if (tid < 128) {
      if (c1[tid]) atomicAdd(&bcnt1[tid], c1[tid]);
      if (c2[tid]) atomicAdd(&bcnt2[tid], c2[tid]);
    }
  } else {
    // score (incl. ||p||) + bf16 cast of x in one pass (x read once)
    int node = (blockIdx.x - 256) * 4 + (tid >> 6);
    int lane = tid & 63;
    if (node >= N) return;
    float4 xv = ((const float4*)(x + (size_t)node * 256))[lane];
    ushort4 hv;
    hv.x = f2bf(xv.x);
    hv.y = f2bf(xv.y);
    hv.z = f2bf(xv.z);
    hv.w = f2bf(xv.w);
    ((ushort4*)(xh + (size_t)node * 256))[lane] = hv;
    float4 pv = ((const float4*)p)[lane];
    float s = xv.x * pv.x + xv.y * pv.y + xv.z * pv.z + xv.w * pv.w;
    float sp = pv.x * pv.x + pv.y * pv.y + pv.z * pv.z + pv.w * pv.w;
#pragma unroll
    for (int off = 32; off > 0; off >>= 1) {
      s += __shfl_down(s, off, 64);
      sp += __shfl_down(sp, off, 64);
    }
    if (lane == 0) score[node] = s / sqrtf(sp);
  }
}

// ---------------- fused B: hist12 (blocks 0..63) || bucket_scan (block 64) -
__global__ __launch_bounds__(256) void fusedB_kernel(const float* __restrict__ score, int n,
                                                     int* __restrict__ gh,
                                                     const int* __restrict__ bcnt1,
                                                     const int* __restrict__ bcnt2,
                                                     int* __restrict__ bbase1,
                                                     int* __restrict__ bbase2,
                                                     int* __restrict__ gcur1,
                                                     int* __restrict__ gcur2,
                                                     int* __restrict__ rowp1,
                                                     int* __restrict__ rowp2, int N, int E) {
  int tid = threadIdx.x;
  if (blockIdx.x < 64) {
    // LDS-aggregated 4096-bin histogram (hot-bin safe)
    __shared__ int lh[4096];
    for (int i = tid; i < 4096; i += 256) lh[i] = 0;
    __syncthreads();
    int idx = blockIdx.x * 256 + tid;
    int stride = 64 * 256;
    for (int i = idx; i < n; i += stride) {
      unsigned key = f2key(score[i]);
      atomicAdd(&lh[key >> 20], 1);
    }
    __syncthreads();
    for (int i = tid; i < 4096; i += 256) {
      int v = lh[i];
      if (v) atomicAdd(&gh[i], v);
    }
  } else {
    // bucket scan -> bases + cursors; rowp[N] = E (low 128 threads active)
    __shared__ int ss[128];
    int v = 0;
    if (tid < 128) { v = (tid < NBUCK) ? bcnt1[tid] : 0; ss[tid] = v; }
    __syncthreads();
    for (int off = 1; off < 128; off <<= 1) {
      int a = 0, b = 0;
      if (tid < 128) { a = ss[tid]; b = (tid >= off) ? ss[tid - off] : 0; }
      __syncthreads();
      if (tid < 128) ss[tid] = a + b;
      __syncthreads();
    }
    if (tid < 128) {
      int excl = ss[tid] - v;
      if (tid < NBUCK) { bbase1[tid] = excl; gcur1[tid] = excl; }
      if (tid == NBUCK - 1) bbase1[NBUCK] = excl + v;
    }
    __syncthreads();
    int v2 = 0;
    if (tid < 128) { v2 = (tid < NBUCK) ? bcnt2[tid] : 0; ss[tid] = v2; }
    __syncthreads();
    for (int off = 1; off < 128; off <<= 1) {
      int a = 0, b = 0;
      if (tid < 128) { a = ss[tid]; b = (tid >= off) ? ss[tid - off] : 0; }
      __syncthreads();
      if (tid < 128) ss[tid] = a + b;
      __syncthreads();
    }
    if (tid < 128) {
      int excl = ss[tid] - v2;
      if (tid < NBUCK) { bbase2[tid] = excl; gcur2[tid] = excl; }
      if (tid == NBUCK - 1) bbase2[NBUCK] = excl + v2;
    }
    if (tid == 0) { rowp1[N] = E; rowp2[N] = E; }
  }
}

// ---------------- fused C (1024 thr): p1 conv [0,nb) | p1 dec [nb,2nb) |
// topk (block 2nb). p1: tile-ranked scatter, 8192 edges/block, 8/thread.
__global__ __launch_bounds__(1024) void fusedC_kernel(const int* __restrict__ ei,
                                                      const float* __restrict__ attr,
                                                      int* __restrict__ gcur1,
                                                      int2* __restrict__ stage1,
                                                      const int* __restrict__ ewi,
                                                      int* __restrict__ gcur2,
                                                      int2* __restrict__ stage2,
                                                      int E, int nb,
                                                      const float* __restrict__ score, int n, int k,
                                                      const int* __restrict__ gh,
                                                      int* __restrict__ perm,
                                                      float* __restrict__ tts) {
  int tid = threadIdx.x;
  if ((int)blockIdx.x < 2 * nb) {
    bool conv = (int)blockIdx.x < nb;
    __shared__ int pcnt[128], pcur[128];
    int base = (conv ? blockIdx.x : blockIdx.x - nb) * 8192;
    int* gcur = conv ? gcur1 : gcur2;
    int2* stage = conv ? stage1 : stage2;
    if (tid < 128) pcnt[tid] = 0;
    __syncthreads();
    int bk[8];
    int2 pl[8];
#pragma unroll
    for (int i = 0; i < 8; ++i) {
      int e = base + i * 1024 + tid;
      bk[i] = -1;
      if (e < E) {
        if (conv) {
          int d = ei[E + e];
          int s = ei[e];
          bk[i] = d >> WSHIFT;
          pl[i] = make_int2(s | ((d & WMASK) << 16), __float_as_int(attr[e]));
        } else {
          int s = ewi[e];
          int d = ewi[E + e];
          bk[i] = s >> WSHIFT;
          pl[i] = make_int2(d | ((s & WMASK) << 16), e);
        }
        atomicAdd(&pcnt[bk[i]], 1);
      }
    }
    __syncthreads();
    if (tid < NBUCK) {
      int c = pcnt[tid];
      pcur[tid] = c ? atomicAdd(&gcur[tid], c) : 0;
    }
    __syncthreads();
#pragma unroll
    for (int i = 0; i < 8; ++i) {
      if (bk[i] >= 0) {
        int pos = atomicAdd(&pcur[bk[i]], 1);
        stage[pos] = pl[i];
      }
    }
  } else {
    // top-k: suffix-scan threshold + collect + bitonic sort
    __shared__ int part[1024];
    __shared__ unsigned sT;
    {
      int b0 = tid * 4;
      int s0 = gh[b0], s1 = gh[b0 + 1], s2 = gh[b0 + 2], s3 = gh[b0 + 3];
      part[tid] = s0 + s1 + s2 + s3;
      __syncthreads();
      for (int off = 1; off < 1024; off <<= 1) {
        int v = part[tid];
        int add = (tid + off < 1024) ? part[tid + off] : 0;
        __syncthreads();
        part[tid] = v + add;
        __syncthreads();
      }
      int sufChunk = part[tid];
      int sufNext = (tid < 1023) ? part[tid + 1] : 0;
      if (sufNext < k && sufChunk >= k) {
        int run = sufNext;
        int b;
        run += s3;
        if (run >= k) b = b0 + 3;
        else {
          run += s2;
          if (run >= k) b = b0 + 2;
          else {
            run += s1;
            b = (run >= k) ? b0 + 1 : b0;
          }
        }
        sT = ((unsigned)b) << 20;
      }
    }
    __syncthreads();
    unsigned T = sT;
    __shared__ unsigned keys[1024];
    __shared__ int idxs[1024];
    __shared__ int cnt;
    if (tid == 0) cnt = 0;
    keys[tid] = 0u;
    idxs[tid] = 0x7fffffff;
    __syncthreads();
    for (int i = tid; i < n; i += 1024) {
      unsigned key = f2key(score[i]);
      if (key >= T) {
        int p = atomicAdd(&cnt, 1);
        if (p < 1024) { keys[p] = key; idxs[p] = i; }
      }
    }
    __syncthreads();
    for (int size = 2; size <= 1024; size <<= 1) {
      for (int stride = size >> 1; stride > 0; stride >>= 1) {
        int j = tid ^ stride;
        if (j > tid) {
          unsigned ka = keys[tid], kb = keys[j];
          int ia = idxs[tid], ib = idxs[j];
          bool aBefore = (ka > kb) || (ka == kb && ia < ib);
          bool up = ((tid & size) == 0);
          if (aBefore != up) {
            keys[tid] = kb; keys[j] = ka;
            idxs[tid] = ib; idxs[j] = ia;
          }
        }
        __syncthreads();
      }
    }
    if (tid < k) {
      int idx = idxs[tid];
      perm[tid] = idx;
      tts[tid] = tanhf(score[idx]);
    }
  }
}

// ---------------- fused D (256 thr): gru (blocks 0..255) || p2 (256..451) --
__global__ __launch_bounds__(256) void fusedD_kernel(const float* __restrict__ x,
                                                     const int* __restrict__ perm,
                                                     const float* __restrict__ tts,
                                                     const float* __restrict__ Wi,
                                                     const float* __restrict__ W_ih,
                                                     const float* __restrict__ W_hh,
                                                     const float* __restrict__ b_ih,
                                                     const float* __restrict__ b_hh,
                                                     unsigned short* __restrict__ WevoT,
                                                     const int2* __restrict__ stage1,
                                                     const int* __restrict__ bbase1,
                                                     int2* __restrict__ esv,
                                                     int* __restrict__ rowp1,
                                                     float* __restrict__ dinv,
                                                     const int2* __restrict__ stage2,
                                                     const int* __restrict__ bbase2,
                                                     int2* __restrict__ eto,
                                                     int* __restrict__ rowp2, int N) {
  int tid = threadIdx.x;
  if (blockIdx.x < 256) {
    // GRU step with x_tilde inline; writes Wevo transposed as bf16
    int i = blockIdx.x, j = tid;
    __shared__ float sx[256], sh[256];
    sx[j] = x[(size_t)perm[i] * 256 + j] * tts[i];
    sh[j] = Wi[i * 256 + j];
    __syncthreads();
    float gi[3], gh[3];
#pragma unroll
    for (int g = 0; g < 3; ++g) {
      int row = g * 256 + j;
      const float4* wi4 = (const float4*)(W_ih + (size_t)row * 256);
      const float4* wh4 = (const float4*)(W_hh + (size_t)row * 256);
      float si = 0.f, s2 = 0.f;
      for (int k4 = 0; k4 < 64; ++k4) {
        float4 wv = wi4[k4];
        float4 hv = wh4[k4];
        int k = k4 * 4;
        si += sx[k] * wv.x + sx[k + 1] * wv.y + sx[k + 2] * wv.z + sx[k + 3] * wv.w;
        s2 += sh[k] * hv.x + sh[k + 1] * hv.y + sh[k + 2] * hv.z + sh[k + 3] * hv.w;
      }
      gi[g] = si + b_ih[row];
      gh[g] = s2 + b_hh[row];
    }
    float r = 1.f / (1.f + expf(-(gi[0] + gh[0])));
    float z = 1.f / (1.f + expf(-(gi[1] + gh[1])));
    float nn = tanhf(gi[2] + r * gh[2]);
    float w = (1.f - z) * nn + z * sh[j];
    WevoT[(size_t)j * 256 + i] = f2bf(w);
  } else {
    // p2: per-bucket node histogram + scan + node-ordered CSR write
    __shared__ int cnt[512];
    __shared__ float degs[512];
    __shared__ int pref[512];
    __shared__ int ss[256];
    int bb2 = blockIdx.x - 256;
    bool isConv = bb2 < NBUCK;
    int b = isConv ? bb2 : bb2 - NBUCK;
    const int2* stage = isConv ? stage1 : stage2;
    const int* bbase = isConv ? bbase1 : bbase2;
    int beg = bbase[b], end = bbase[b + 1];
    int node0 = b << WSHIFT;
    cnt[tid] = 0; cnt[tid + 256] = 0;
    degs[tid] = 0.f; degs[tid + 256] = 0.f;
    __syncthreads();
    for (int j = beg + tid; j < end; j += 256) {
      int2 p = stage[j];
      int loc = p.x >> 16;
      atomicAdd(&cnt[loc], 1);
      if (isConv) atomicAdd(&degs[loc], __int_as_float(p.y));
    }
    __syncthreads();
    int c0 = cnt[2 * tid], c1 = cnt[2 * tid + 1];
    ss[tid] = c0 + c1;
    __syncthreads();
    for (int off = 1; off < 256; off <<= 1) {
      int a = ss[tid];
      int bsum = (tid >= off) ? ss[tid - off] : 0;
      __syncthreads();
      ss[tid] = a + bsum;
      __syncthreads();
    }
    int excl = (tid ? ss[tid - 1] : 0);
    pref[2 * tid] = excl;
    pref[2 * tid + 1] = excl + c0;
    __syncthreads();
#pragma unroll
    for (int h = 0; h < 2; ++h) {
      int i = tid + h * 256;
      int node = node0 + i;
      if (node < N) {
        if (isConv) {
          rowp1[node] = beg + pref[i];
          float d = degs[i];
          dinv[node] = d > 0.f ? 1.f / sqrtf(d) : 0.f;
        } else {
          rowp2[node] = beg + pref[i];
        }
      }
    }
    __syncthreads();
    int2* outb = isConv ? esv : eto;
    for (int j = beg + tid; j < end; j += 256) {
      int2 p = stage[j];
      int loc = p.x >> 16;
      int pos = beg + atomicAdd(&pref[loc], 1);
      outb[pos] = make_int2(p.x & 0xFFFF, p.y);
    }
  }
}

// ---------------------------------------------------------------------------
// m97-structure bf16 MFMA GEMM: per blockIdx.y,
//   C[M,256] = A[M,256] @ (BT[by*256 .. by*256+255][256])^T   (bf16 in/out)
// 128x256 tile, 8 waves (2 wm x 4 wn), BK=32, global_load_lds staging,
// 2-barrier K-loop. Rows >= M read in-workspace garbage (never written back).
// ---------------------------------------------------------------------------
__global__ __launch_bounds__(512) void mfma_gemm128(const unsigned short* __restrict__ A,
                                                    const unsigned short* __restrict__ BT,
                                                    unsigned short* __restrict__ C1,
                                                    unsigned short* __restrict__ C2,
                                                    int M) {
  __shared__ unsigned short sA[128 * 32];
  __shared__ unsigned short sB[256 * 32];
  int tid = threadIdx.x;
  int wave = tid >> 6, lane = tid & 63;
  int quad = lane >> 4, r16 = lane & 15;
  int wm = wave >> 2, wn = wave & 3;
  int mbase = blockIdx.x * 128;
  const unsigned short* Bt = BT + ((size_t)blockIdx.y << 16);
  unsigned short* Cout = blockIdx.y ? C2 : C1;

  // staging map: thread t stages 16B -> LDS byte t*16 (= row t>>2, colq t&3)
  int srow = tid >> 2, scolq = tid & 3;
  const unsigned short* gA = A + (size_t)(mbase + srow) * 256 + scolq * 8;
  const unsigned short* gB0 = Bt + (size_t)srow * 256 + scolq * 8;
  const unsigned short* gB1 = Bt + (size_t)(128 + srow) * 256 + scolq * 8;
  unsigned short* lA = sA + wave * 512;          // wave-uniform LDS bases
  unsigned short* lB0 = sB + wave * 512;
  unsigned short* lB1 = sB + 4096 + wave * 512;

  f32x4 acc[4][4];
#pragma unroll
  for (int i = 0; i < 4; ++i)
#pragma unroll
    for (int j = 0; j < 4; ++j) acc[i][j] = (f32x4){0.f, 0.f, 0.f, 0.f};

  const unsigned short* pA = sA + (wm * 64 + r16) * 32 + quad * 8;
  const unsigned short* pB = sB + (wn * 64 + r16) * 32 + quad * 8;

  for (int k0 = 0; k0 < 256; k0 += 32) {
    if (k0) __syncthreads();              // prior compute done before overwrite
    gload16(gA + k0, lA);
    gload16(gB0 + k0, lB0);
    gload16(gB1 + k0, lB1);
    __syncthreads();                      // drains vmcnt -> staging complete
    bf16x8 af[4], bfr[4];
#pragma unroll
    for (int mt = 0; mt < 4; ++mt) af[mt] = *(const bf16x8*)(pA + mt * 512);
#pragma unroll
    for (int nt = 0; nt < 4; ++nt) bfr[nt] = *(const bf16x8*)(pB + nt * 512);
#pragma unroll
    for (int mt = 0; mt < 4; ++mt)
#pragma unroll
      for (int nt = 0; nt < 4; ++nt)
        acc[mt][nt] = __builtin_amdgcn_mfma_f32_16x16x32_bf16(af[mt], bfr[nt], acc[mt][nt], 0, 0, 0);
  }
#pragma unroll
  for (int mt = 0; mt < 4; ++mt) {
#pragma unroll
    for (int rr = 0; rr < 4; ++rr) {
      int grow = mbase + wm * 64 + mt * 16 + quad * 4 + rr;
      if (grow < M) {
#pragma unroll
        for (int nt = 0; nt < 4; ++nt)
          Cout[(size_t)grow * 256 + wn * 64 + nt * 16 + r16] = f2bf(acc[mt][nt][rr]);
      }
    }
  }
}

// one wave per dst node, quad decomposition: 16 lanes/edge x 4 edges/group.
// Per 64-edge chunk: lane l coalesced-loads meta esv[cb+l] and applies
// dinv[src] once (L2-resident), then stage refills broadcast src/v via shfl
// (refill chain rows-only). 3-stage in-place prefetch.
__global__ __launch_bounds__(256) void gcn_gather(const unsigned short* __restrict__ xw,
                                                  const int* __restrict__ row_ptr,
                                                  const int2* __restrict__ esv,
                                                  const float* __restrict__ dinv,
                                                  unsigned short* __restrict__ ne, int N) {
  int node = blockIdx.x * 4 + (threadIdx.x >> 6);
  int lane = threadIdx.x & 63;
  int g = lane & 15, q = lane >> 4;
  if (node >= N) return;
  int beg = row_ptr[node], end = row_ptr[node + 1];
  float acc[16];
#pragma unroll
  for (int c = 0; c < 16; ++c) acc[c] = 0.f;
  const unsigned short* xb = xw + g * 16;

  for (int cb = beg; cb < end; cb += 64) {
    int cend = cb + 64 < end ? cb + 64 : end;
    int me = cb + lane;
    int2 mm = (me < cend) ? esv[me] : make_int2(0, 0);
    int mx = mm.x;
    float mv = __int_as_float(mm.y) * dinv[mx];

    float vA = 0.f, vB = 0.f, vC = 0.f;
    u16x8 rAa, rAb, rBa, rBb, rCa, rCb;
    {
      int e = cb + q;
      int sx = __shfl(mx, q, 64);
      float tv = __shfl(mv, q, 64);
      vA = (e < cend) ? tv : 0.f;
      rAa = *(const u16x8*)(xb + (size_t)sx * 256);
      rAb = *(const u16x8*)(xb + (size_t)sx * 256 + 8);
    }
    if (cb + 4 < cend) {
      int e = cb + 4 + q;
      int sx = __shfl(mx, 4 + q, 64);
      float tv = __shfl(mv, 4 + q, 64);
      vB = (e < cend) ? tv : 0.f;
      rBa = *(const u16x8*)(xb + (size_t)sx * 256);
      rBb = *(const u16x8*)(xb + (size_t)sx * 256 + 8);
    } else { rBa = rAa; rBb = rAb; }
    if (cb + 8 < cend) {
      int e = cb + 8 + q;
      int sx = __shfl(mx, 8 + q, 64);
      float tv = __shfl(mv, 8 + q, 64);
      vC = (e < cend) ? tv : 0.f;
      rCa = *(const u16x8*)(xb + (size_t)sx * 256);
      rCb = *(const u16x8*)(xb + (size_t)sx * 256 + 8);
    } else { rCa = rAa; rCb = rAb; }

    for (int jb = cb; jb < cend; jb += 12) {
      // consume A, refill A <- jb+12
#pragma unroll
      for (int c = 0; c < 8; ++c) acc[c] += bf2f(rAa[c]) * vA;
#pragma unroll
      for (int c = 0; c < 8; ++c) acc[8 + c] += bf2f(rAb[c]) * vA;
      vA = 0.f;
      if (jb + 12 < cend) {
        int e = jb + 12 + q;
        int idx = (e - cb) & 63;
        int sx = __shfl(mx, idx, 64);
        float tv = __shfl(mv, idx, 64);
        vA = (e < cend) ? tv : 0.f;
        rAa = *(const u16x8*)(xb + (size_t)sx * 256);
        rAb = *(const u16x8*)(xb + (size_t)sx * 256 + 8);
      }
      // consume B, refill B <- jb+16
#pragma unroll
      for (int c = 0; c < 8; ++c) acc[c] += bf2f(rBa[c]) * vB;
#pragma unroll
      for (int c = 0; c < 8; ++c) acc[8 + c] += bf2f(rBb[c]) * vB;
      vB = 0.f;
      if (jb + 16 < cend) {
        int e = jb + 16 + q;
        int idx = (e - cb) & 63;
        int sx = __shfl(mx, idx, 64);
        float tv = __shfl(mv, idx, 64);
        vB = (e < cend) ? tv : 0.f;
        rBa = *(const u16x8*)(xb + (size_t)sx * 256);
        rBb = *(const u16x8*)(xb + (size_t)sx * 256 + 8);
      }
      // consume C, refill C <- jb+20
#pragma unroll
      for (int c = 0; c < 8; ++c) acc[c] += bf2f(rCa[c]) * vC;
#pragma unroll
      for (int c = 0; c < 8; ++c) acc[8 + c] += bf2f(rCb[c]) * vC;
      vC = 0.f;
      if (jb + 20 < cend) {
        int e = jb + 20 + q;
        int idx = (e - cb) & 63;
        int sx = __shfl(mx, idx, 64);
        float tv = __shfl(mv, idx, 64);
        vC = (e < cend) ? tv : 0.f;
        rCa = *(const u16x8*)(xb + (size_t)sx * 256);
        rCb = *(const u16x8*)(xb + (size_t)sx * 256 + 8);
      }
    }
  }
  // cross-quad combine (each quad holds a partial over the same channels)
#pragma unroll
  for (int c = 0; c < 16; ++c) {
    acc[c] += __shfl_xor(acc[c], 16, 64);
    acc[c] += __shfl_xor(acc[c], 32, 64);
  }
  if (q == 0) {
    float dd = dinv[node];
    u16x8 o0, o1;
#pragma unroll
    for (int c = 0; c < 8; ++c) {
      o0[c] = f2bf(acc[c] * dd);
      o1[c] = f2bf(acc[8 + c] * dd);
    }
    *(u16x8*)(ne + (size_t)node * 256 + g * 16) = o0;
    *(u16x8*)(ne + (size_t)node * 256 + g * 16 + 8) = o1;
  }
}

// decode grouped by src, one wave per node, quad decomposition. Per-chunk
// meta preload + shfl broadcast; 3-stage in-place prefetch; DPP row_ror
// reduce. A[s]+b1 and w2 register-resident per lane (16 channels).
__global__ __launch_bounds__(256) void edge_decode_csr(const unsigned short* __restrict__ A,
                                                       const unsigned short* __restrict__ Bm,
                                                       const int* __restrict__ row_ptr,
                                                       const int2* __restrict__ eto,
                                                       const float* __restrict__ b1,
                                                       const float* __restrict__ w2,
                                                       const float* __restrict__ b2,
                                                       float* __restrict__ out, int N) {
  int node = blockIdx.x * 4 + (threadIdx.x >> 6);
  int lane = threadIdx.x & 63;
  int g = lane & 15, q = lane >> 4;
  if (node >= N) return;
  int beg = row_ptr[node], end = row_ptr[node + 1];
  if (beg >= end) return;
  float a[16], w[16];
  {
    u16x8 a0 = *(const u16x8*)(A + (size_t)node * 256 + g * 16);
    u16x8 a1 = *(const u16x8*)(A + (size_t)node * 256 + g * 16 + 8);
    const float4* bp = (const float4*)(b1 + g * 16);
    const float4* wp = (const float4*)(w2 + g * 16);
#pragma unroll
    for (int i = 0; i < 4; ++i) {
      float4 bv = bp[i];
      float4 wv = wp[i];
      a[i * 4 + 0] = (i < 2 ? bf2f(a0[i * 4 + 0]) : bf2f(a1[i * 4 - 8])) + bv.x;
      a[i * 4 + 1] = (i < 2 ? bf2f(a0[i * 4 + 1]) : bf2f(a1[i * 4 - 7])) + bv.y;
      a[i * 4 + 2] = (i < 2 ? bf2f(a0[i * 4 + 2]) : bf2f(a1[i * 4 - 6])) + bv.z;
      a[i * 4 + 3] = (i < 2 ? bf2f(a0[i * 4 + 3]) : bf2f(a1[i * 4 - 5])) + bv.w;
      w[i * 4 + 0] = wv.x;
      w[i * 4 + 1] = wv.y;
      w[i * 4 + 2] = wv.z;
      w[i * 4 + 3] = wv.w;
    }
  }
  float base = b2[0];
  const unsigned short* Bb = Bm + g * 16;

  for (int cb = beg; cb < end; cb += 64) {
    int cend = cb + 64 < end ? cb + 64 : end;
    int me = cb + lane;
    int2 mm = (me < cend) ? eto[me] : make_int2(0, 0);
    int mx = mm.x, my = mm.y;

    bool okA = false, okB = false, okC = false;
    int oA = 0, oB = 0, oC = 0;
    u16x8 rAa, rAb, rBa, rBb, rCa, rCb;
    {
      int e = cb + q;
      int sx = __shfl(mx, q, 64);
      oA = __shfl(my, q, 64);
      okA = e < cend;
      rAa = *(const u16x8*)(Bb + (size_t)sx * 256);
      rAb = *(const u16x8*)(Bb + (size_t)sx * 256 + 8);
    }
    if (cb + 4 < cend) {
      int e = cb + 4 + q;
      int sx = __shfl(mx, 4 + q, 64);
      oB = __shfl(my, 4 + q, 64);
      okB = e < cend;
      rBa = *(const u16x8*)(Bb + (size_t)sx * 256);
      rBb = *(const u16x8*)(Bb + (size_t)sx * 256 + 8);
    } else { rBa = rAa; rBb = rAb; }
    if (cb + 8 < cend) {
      int e = cb + 8 + q;
      int sx = __shfl(mx, 8 + q, 64);
      oC = __shfl(my, 8 + q, 64);
      okC = e < cend;
      rCa = *(const u16x8*)(Bb + (size_t)sx * 256);
      rCb = *(const u16x8*)(Bb + (size_t)sx * 256 + 8);
    } else { rCa = rAa; rCb = rAb; }

    for (int jb = cb; jb < cend; jb += 12) {
      // consume A
      {
        float s0 = 0.f, s1 = 0.f;
#pragma unroll
        for (int c = 0; c < 8; ++c) s0 += fmaxf(a[c] + bf2f(rAa[c]), 0.f) * w[c];
#pragma unroll
        for (int c = 0; c < 8; ++c) s1 += fmaxf(a[8 + c] + bf2f(rAb[c]), 0.f) * w[8 + c];
        float s = s0 + s1;
        s = dpp_add<0x128>(s);  // row_ror:8
        s = dpp_add<0x124>(s);  // row_ror:4
        s = dpp_add<0x122>(s);  // row_ror:2
        s = dpp_add<0x121>(s);  // row_ror:1
        if (g == 0 && okA) out[oA] = s + base;
      }
      // refill A <- jb+12
      okA = false;
      if (jb + 12 < cend) {
        int e = jb + 12 + q;
        int idx = (e - cb) & 63;
        int sx = __shfl(mx, idx, 64);
        oA = __shfl(my, idx, 64);
        okA = e < cend;
        rAa = *(const u16x8*)(Bb + (size_t)sx * 256);
        rAb = *(const u16x8*)(Bb + (size_t)sx * 256 + 8);
      }
      // consume B
      {
        float s0 = 0.f, s1 = 0.f;
#pragma unroll
        for (int c = 0; c < 8; ++c) s0 += fmaxf(a[c] + bf2f(rBa[c]), 0.f) * w[c];
#pragma unroll
        for (int c = 0; c < 8; ++c) s1 += fmaxf(a[8 + c] + bf2f(rBb[c]), 0.f) * w[8 + c];
        float s = s0 + s1;
        s = dpp_add<0x128>(s);
        s = dpp_add<0x124>(s);
        s = dpp_add<0x122>(s);
        s = dpp_add<0x121>(s);
        if (g == 0 && okB) out[oB] = s + base;
      }
      // refill B <- jb+16
      okB = false;
      if (jb + 16 < cend) {
        int e = jb + 16 + q;
        int idx = (e - cb) & 63;
        int sx = __shfl(mx, idx, 64);
        oB = __shfl(my, idx, 64);
        okB = e < cend;
        rBa = *(const u16x8*)(Bb + (size_t)sx * 256);
        rBb = *(const u16x8*)(Bb + (size_t)sx * 256 + 8);
      }
      // consume C
      {
        float s0 = 0.f, s1 = 0.f;
#pragma unroll
        for (int c = 0; c < 8; ++c) s0 += fmaxf(a[c] + bf2f(rCa[c]), 0.f) * w[c];
#pragma unroll
        for (int c = 0; c < 8; ++c) s1 += fmaxf(a[8 + c] + bf2f(rCb[c]), 0.f) * w[8 + c];
        float s = s0 + s1;
        s = dpp_add<0x128>(s);
        s = dpp_add<0x124>(s);
        s = dpp_add<0x122>(s);
        s = dpp_add<0x121>(s);
        if (g == 0 && okC) out[oC] = s + base;
      }
      // refill C <- jb+20
      okC = false;
      if (jb + 20 < cend) {
        int e = jb + 20 + q;
        int idx = (e - cb) & 63;
        int sx = __shfl(mx, idx, 64);
        oC = __shfl(my, idx, 64);
        okC = e < cend;
        rCa = *(const u16x8*)(Bb + (size_t)sx * 256);
        rCb = *(const u16x8*)(Bb + (size_t)sx * 256 + 8);
      }
    }
  }
}

extern "C" void kernel_launch(void* const* d_in, const int* in_sizes, int n_in,
                              void* d_out, int out_size, void* d_ws, size_t ws_size,
                              hipStream_t stream) {
  const float* x      = (const float*)d_in[0];
  const int*   ei     = (const int*)d_in[1];
  const float* attr   = (const float*)d_in[2];
  const int*   ewi    = (const int*)d_in[3];
  const float* p_pool = (const float*)d_in[4];
  const float* W_ih   = (const float*)d_in[5];
  const float* W_hh   = (const float*)d_in[6];
  const float* b_ih   = (const float*)d_in[7];
  const float* b_hh   = (const float*)d_in[8];
  const float* W_init = (const float*)d_in[9];
  const float* lin1_w = (const float*)d_in[10];
  const float* lin1_b = (const float*)d_in[11];
  const float* lin2_w = (const float*)d_in[12];
  const float* lin2_b = (const float*)d_in[13];
  float* out = (float*)d_out;

  const int C = 256;
  const int N = in_sizes[0] / C;   // 50000
  const int E = in_sizes[2];       // 800000

  // ---- workspace layout (256B aligned) ----
  char* ws = (char*)d_ws;
  size_t off = 0;
  auto alloc = [&](size_t bytes) {
    size_t o = off;
    off = (off + bytes + 255) & ~(size_t)255;
    return o;
  };
  float*          score  = (float*)(ws + alloc((size_t)N * 4));
  int*            perm   = (int*)(ws + alloc(C * 4));
  float*          tts    = (float*)(ws + alloc(C * 4));
  unsigned short* WevoT  = (unsigned short*)(ws + alloc((size_t)C * C * 2));
  unsigned short* WAB    = (unsigned short*)(ws + alloc((size_t)2 * C * C * 2));
  // contiguous zero region: ghist | bcnt1 | bcnt2
  int   zeroInts = 4096 + 128 + 128;
  char* zbase    = ws + alloc((size_t)zeroInts * 4);
  int* ghist = (int*)zbase;
  int* bcnt1 = (int*)(zbase + 4096 * 4);
  int* bcnt2 = (int*)(zbase + 4096 * 4 + 128 * 4);
  int*            bbase1 = (int*)(ws + alloc((NBUCK + 1) * 4));
  int*            bbase2 = (int*)(ws + alloc((NBUCK + 1) * 4));
  int*            gcur1  = (int*)(ws + alloc(128 * 4));
  int*            gcur2  = (int*)(ws + alloc(128 * 4));
  float*          dinv   = (float*)(ws + alloc((size_t)N * 4));
  int*            rowp1  = (int*)(ws + alloc((size_t)(N + 1) * 4));
  int*            rowp2  = (int*)(ws + alloc((size_t)(N + 1) * 4));
  int2*           stage1 = (int2*)(ws + alloc((size_t)E * 8));
  int2*           stage2 = (int2*)(ws + alloc((size_t)E * 8));
  int2*           esv    = (int2*)(ws + alloc((size_t)E * 8));
  int2*           eto    = (int2*)(ws + alloc((size_t)E * 8));
  unsigned short* xh     = (unsigned short*)(ws + alloc((size_t)N * C * 2));
  unsigned short* xwh    = (unsigned short*)(ws + alloc((size_t)N * C * 2));
  unsigned short* Bbf    = (unsigned short*)(ws + alloc((size_t)N * C * 2));
  // aliases (stream-ordered producers/consumers):
  unsigned short* ne  = xh;   // xh dead after GEMM1
  unsigned short* Abf = xwh;  // xwh dead after gather

  int nz4 = (zeroInts + 3) / 4;
  int nbP1 = (E + 8191) / 8192;   // 98 (1024-thread p1 blocks)

  // 1) init: lin1 cast (512 blocks) + zero ghist/bcnt (tail blocks)
  init_kernel<<<512 + (nz4 + 255) / 256, 256, 0, stream>>>(lin1_w, WAB, (int4*)zbase, nz4);

  // 2) A: bucket_hist (256 blocks) || score_cast (12500 blocks)
  fusedA_kernel<<<256 + (N + 3) / 4, 256, 0, stream>>>(x, p_pool, score, xh, N,
                                                       ei, ewi, bcnt1, bcnt2, E);

  // 3) B: hist12 (64 blocks) || bucket_scan (block 64)
  fusedB_kernel<<<65, 256, 0, stream>>>(score, N, ghist, bcnt1, bcnt2,
                                        bbase1, bbase2, gcur1, gcur2,
                                        rowp1, rowp2, N, E);

  // 4) C: p1 conv+dec (2*98 blocks, 8192 edges each) || topk (block 196)
  fusedC_kernel<<<2 * nbP1 + 1, 1024, 0, stream>>>(ei, attr, gcur1, stage1,
                                                   ewi, gcur2, stage2, E, nbP1,
                                                   score, N, C, ghist, perm, tts);

  // 5) D: gru (256 blocks) || p2 (196 blocks)
  fusedD_kernel<<<256 + 2 * NBUCK, 256, 0, stream>>>(x, perm, tts, W_init,
                                                     W_ih, W_hh, b_ih, b_hh, WevoT,
                                                     stage1, bbase1, esv, rowp1, dinv,
                                                     stage2, bbase2, eto, rowp2, N);

  // 6) xw = x @ Wevo (128x256-tile MFMA, global_load_lds staging)
  mfma_gemm128<<<dim3((N + 127) / 128, 1), 512, 0, stream>>>(xh, WevoT, xwh, xwh, N);

  // 7) gather (per-node waves; dinv applied at meta preload)
  gcn_gather<<<(N + 3) / 4, 256, 0, stream>>>(xwh, rowp1, esv, dinv, ne, N);

  // 8) decoder projections: stacked BT (WA^T | WB^T), gridDim.y = 2
  mfma_gemm128<<<dim3((N + 127) / 128, 2), 512, 0, stream>>>(ne, WAB, Abf, Bbf, N);

  // 9) edge decode (per-node waves, 3-stage prefetch + DPP reduce)
  edge_decode_csr<<<(N + 3) / 4, 256, 0, stream>>>(Abf, Bbf, rowp2, eto,
                                                   lin1_b, lin2_w, lin2_b, out, N);
}